// Round 21
// baseline (372.292 us; speedup 1.0000x reference)
//
#include <hip/hip_runtime.h>
#include <hip/hip_bf16.h>

#define N_NODES 100000
#define N_EDGES 3200000
#define FEAT 256
#define HIDDEN 32
#define EMBED 16
#define NPB 128                                // nodes per bin
#define NBIN ((N_NODES + NPB - 1) / NPB)       // 782
#define CAPB 4608                              // bin capacity (mean 4096 + 8 sigma)
#define OCAP 8192                              // overflow list capacity
#define GR 128                                 // gemm1 tile rows
#define G1N 32                                 // nodes per gather1 block
#define G1CAP 2048                             // LDS entries
#define G2N 64                                 // nodes per gather2 block
#define G2CAP 3072                             // LDS entries
#define PEPB 3072                              // edges per partition block
#define PBLK ((N_EDGES + PEPB - 1) / PEPB)     // 1042
#define OMS 784                                // offm row stride (782 bins + sentinel + pad)
#define RPT 5                                  // runs per thread in k_build (5*256 >= 1042)
#define NSK (NPB * 8)                          // sub-keys: node x 8 src-tiles

// ---------------- pass 1: per-block bin-grouped chunk + offset row ----------
// (k_zero folded in: block 0 zeroes the overflow cursor; no reader until build)
__global__ __launch_bounds__(256, 4) void k_part(
        const int* __restrict__ row, const int* __restrict__ col,
        const float* __restrict__ ew, int* __restrict__ offm,
        int2* __restrict__ chunks, int* __restrict__ ocur) {
    __shared__ int2 sed[PEPB];                 // 24576 B staged edges (grouped)
    __shared__ int shist[NBIN];                // counts -> local excl offsets
    __shared__ int scur[NBIN];                 // scan scratch, then cursors
    const int tid = threadIdx.x;
    const int blk = blockIdx.x;
    const int e0 = blk * PEPB;
    const int ne = min(PEPB, N_EDGES - e0);
    if (blk == 0 && tid == 0) *ocur = 0;

    for (int i = tid; i < NBIN; i += 256) shist[i] = 0;
    __syncthreads();
    for (int i = tid; i < ne; i += 256) atomicAdd(&shist[col[e0 + i] >> 7], 1);
    __syncthreads();
    int l[4];
    int s = 0;
#pragma unroll
    for (int k = 0; k < 4; ++k) {
        int b = tid * 4 + k;
        l[k] = (b < NBIN) ? shist[b] : 0;
        s += l[k];
    }
    scur[tid] = s;
    __syncthreads();
    for (int d = 1; d < 256; d <<= 1) {
        int t = (tid >= d) ? scur[tid - d] : 0;
        __syncthreads();
        scur[tid] += t;
        __syncthreads();
    }
    int ex = scur[tid] - s;
    __syncthreads();
#pragma unroll
    for (int k = 0; k < 4; ++k) {
        int b = tid * 4 + k;
        if (b < NBIN) {
            shist[b] = ex;
            scur[b] = ex;
            ex += l[k];
        }
    }
    __syncthreads();
    for (int b = tid; b < NBIN; b += 256) offm[blk * OMS + b] = shist[b];
    if (tid == 0) offm[blk * OMS + NBIN] = ne;
    for (int i = tid; i < ne; i += 256) {
        int e = e0 + i;
        int c = col[e];
        int b = c >> 7;
        int p = atomicAdd(&scur[b], 1);        // LDS atomic
        sed[p] = make_int2(((c & (NPB - 1)) << 17) | row[e], __float_as_int(ew[e]));
    }
    __syncthreads();
    for (int i = tid; i < ne; i += 256) chunks[(size_t)blk * PEPB + i] = sed[i];
}

// ---------------- pass 2: per-bin gather-from-chunks + group + deg + off2 ----
__global__ __launch_bounds__(256) void k_build(
        const int* __restrict__ offm, const int2* __restrict__ chunks,
        int2* __restrict__ binned, float* __restrict__ deg,
        int2* __restrict__ off2, int* __restrict__ binTot,
        int* __restrict__ ocur, int4* __restrict__ olist) {
    __shared__ int2 se[CAPB];                      // 36864 B
    __shared__ int scnt[NSK], scur2[NSK];          // 2 x 4096 B
    __shared__ float sdeg[NPB];
    __shared__ int spart[256];
    const int bin = blockIdx.x, tid = threadIdx.x;
    const size_t base = (size_t)bin * CAPB;

    for (int i = tid; i < NSK; i += 256) scnt[i] = 0;
    for (int i = tid; i < NPB; i += 256) sdeg[i] = 0.f;
    int st[RPT], ln[RPT];
    int s = 0;
#pragma unroll
    for (int r = 0; r < RPT; ++r) {
        int k = tid * RPT + r;
        int a = 0, b2 = 0;
        if (k < PBLK) {
            a = offm[k * OMS + bin];
            b2 = offm[k * OMS + bin + 1];
        }
        st[r] = a;
        ln[r] = b2 - a;
        s += ln[r];
    }
    spart[tid] = s;
    __syncthreads();
    for (int d = 1; d < 256; d <<= 1) {
        int t = (tid >= d) ? spart[tid - d] : 0;
        __syncthreads();
        spart[tid] += t;
        __syncthreads();
    }
    int ex = spart[tid] - s;
    const int nTot = spart[255];
    const int n = min(nTot, CAPB);
    int dp = ex;
#pragma unroll
    for (int r = 0; r < RPT; ++r) {
        int k = tid * RPT + r;
        if (k < PBLK) {
            const int2* src = chunks + (size_t)k * PEPB + st[r];
            for (int j = 0; j < ln[r]; ++j) {
                int2 v = src[j];
                int lc = v.x >> 17;
                int dst = dp + j;
                if (dst < CAPB) {
                    se[dst] = v;
                    atomicAdd(&scnt[lc * 8 + ((v.x & 0x1FFFF) >> 14)], 1);
                    atomicAdd(&sdeg[lc], __int_as_float(v.y));
                } else {
                    int q = atomicAdd(ocur, 1);
                    if (q < OCAP)
                        olist[q] = make_int4(v.x & 0x1FFFF, bin * NPB + lc, v.y, 0);
                }
            }
            dp += ln[r];
        }
    }
    __syncthreads();
    int l0 = scnt[tid * 4], l1 = scnt[tid * 4 + 1],
        l2 = scnt[tid * 4 + 2], l3 = scnt[tid * 4 + 3];
    int s2 = l0 + l1 + l2 + l3;
    spart[tid] = s2;
    __syncthreads();
    for (int d = 1; d < 256; d <<= 1) {
        int t = (tid >= d) ? spart[tid - d] : 0;
        __syncthreads();
        spart[tid] += t;
        __syncthreads();
    }
    int ex2 = spart[tid] - s2;
    scnt[tid * 4] = ex2;
    scnt[tid * 4 + 1] = ex2 + l0;
    scnt[tid * 4 + 2] = ex2 + l0 + l1;
    scnt[tid * 4 + 3] = ex2 + l0 + l1 + l2;
    __syncthreads();
    for (int i = tid; i < NSK; i += 256) scur2[i] = scnt[i];
    __syncthreads();
    if (tid < NPB) {
        int node = bin * NPB + tid;
        if (node < N_NODES) {
            int stn = scnt[tid * 8];
            int en = (tid == NPB - 1) ? n : scnt[(tid + 1) * 8];
            off2[node] = make_int2((int)base + stn, en - stn);
            deg[node] = sdeg[tid] + 1.0f;  // + self loop
        }
    }
    if (tid == 0) binTot[bin] = n;
    __syncthreads();
    for (int i = tid; i < n; i += 256) {
        int2 v = se[i];
        int lc = v.x >> 17, src2 = v.x & 0x1FFFF;
        int p = atomicAdd(&scur2[lc * 8 + (src2 >> 14)], 1);  // LDS atomic
        binned[base + p] = make_int2(src2, v.y);
    }
}

__global__ void k_degover(const int* __restrict__ ocur, const int4* __restrict__ olist,
                          float* __restrict__ deg) {
    int p = blockIdx.x * blockDim.x + threadIdx.x;
    int n = min(*ocur, OCAP);
    if (p < n) { int4 t = olist[p]; unsafeAtomicAdd(&deg[t.y], __int_as_float(t.z)); }
}

__global__ void k_dis(float* __restrict__ deg) {
    int i = blockIdx.x * blockDim.x + threadIdx.x;
    if (i < N_NODES) {
        float d = deg[i];
        deg[i] = (d > 0.0f) ? rsqrtf(d) : 0.0f;
    }
}

// ---------------- fold dis[src] into csr weights in-place ----------------
__global__ void k_wnorm(const int* __restrict__ binTot, int2* __restrict__ csr,
                        const float* __restrict__ dis) {
    int bin = blockIdx.x;
    int n = binTot[bin];
    size_t base = (size_t)bin * CAPB;
    for (int i = threadIdx.x; i < n; i += 256) {
        int2 v = csr[base + i];
        float w = __int_as_float(v.y) * dis[v.x];
        csr[base + i] = make_int2(v.x, __float_as_int(w));
    }
}

// ---------------- layer 1 GEMM: h = x @ W1^T ----------------
// x pipelined through LDS (18.4KB only); W read DIRECTLY from global:
// 8-lane same-address float4 broadcasts, L1/L2-resident (32KB read-only).
// Halves LDS-read count vs LDS-W version.
__global__ __launch_bounds__(256) void k_gemm1(
        const float* __restrict__ x, const float* __restrict__ W1,
        float* __restrict__ h) {
    __shared__ float sx[GR][36];       // 18432 B (stride 36 = 4-bank shift/row)

    const int tid = threadIdx.x;
    const size_t base = (size_t)blockIdx.x * GR;
    const float4* x4 = (const float4*)x;
    const float4* w4 = (const float4*)W1;
    const int rs = tid >> 3;   // staging row group: rows rs+32m
    const int ks = tid & 7;    // staging kq within phase

    // prologue: phase-0 x into regs, then LDS
    float4 stg[4];
#pragma unroll
    for (int m = 0; m < 4; ++m) {
        int rr = rs + 32 * m;
        stg[m] = make_float4(0.f, 0.f, 0.f, 0.f);
        if (base + rr < N_NODES) stg[m] = x4[(base + rr) * 64 + ks];
    }
#pragma unroll
    for (int m = 0; m < 4; ++m) *(float4*)&sx[rs + 32 * m][ks * 4] = stg[m];
    __syncthreads();

    const int r0 = tid >> 3;
    const int c0 = tid & 7;
    float acc[4][4] = {};

    for (int p = 0; p < 8; ++p) {
        if (p < 7) {
            // issue next phase's x loads (in flight across the compute below)
#pragma unroll
            for (int m = 0; m < 4; ++m) {
                int rr = rs + 32 * m;
                stg[m] = make_float4(0.f, 0.f, 0.f, 0.f);
                if (base + rr < N_NODES) stg[m] = x4[(base + rr) * 64 + (p + 1) * 8 + ks];
            }
        }
#pragma unroll
        for (int kq = 0; kq < 8; ++kq) {
            float4 xa[4], wv[4];
#pragma unroll
            for (int m = 0; m < 4; ++m) xa[m] = *(const float4*)&sx[r0 + 32 * m][kq * 4];
#pragma unroll
            for (int j = 0; j < 4; ++j) wv[j] = w4[(c0 + 8 * j) * 64 + p * 8 + kq];
#pragma unroll
            for (int m = 0; m < 4; ++m)
#pragma unroll
                for (int j = 0; j < 4; ++j)
                    acc[m][j] += xa[m].x * wv[j].x + xa[m].y * wv[j].y +
                                 xa[m].z * wv[j].z + xa[m].w * wv[j].w;
        }
        __syncthreads();
        if (p < 7) {
#pragma unroll
            for (int m = 0; m < 4; ++m) *(float4*)&sx[rs + 32 * m][ks * 4] = stg[m];
            __syncthreads();
        }
    }

#pragma unroll
    for (int m = 0; m < 4; ++m) {
        size_t r = base + r0 + 32 * m;
        if (r < N_NODES) {
#pragma unroll
            for (int j = 0; j < 4; ++j) h[r * HIDDEN + c0 + 8 * j] = acc[m][j];
        }
    }
}

// ---- FUSED layer-1 gather + gemm2: h2 = relu(gcn1(h)) @ W2^T ----
// sw2 padded to stride 33: epilogue reads now conflict-free (was 8-way).
__global__ __launch_bounds__(256) void k_gather1(
        const int2* __restrict__ off2, const int2* __restrict__ csr,
        const float* __restrict__ h, const float* __restrict__ dis,
        const float* __restrict__ b1, const float* __restrict__ W2,
        const int* __restrict__ ocur, const int4* __restrict__ olist,
        float* __restrict__ h2) {
    __shared__ int2 sc[G1CAP];                 // 16384 B csr window
    __shared__ float sw2[EMBED][HIDDEN + 1];   //  2112 B (stride 33: bank = f+k)
    __shared__ float sout[G1N][HIDDEN + 1];    //  4224 B relu(out1)
    __shared__ int s_start, s_n, s_ov;
    const int tid = threadIdx.x;
    const int node0 = blockIdx.x * G1N;        // 100000 = 32*3125 exact
    if (tid == 0) {
        int2 a = off2[node0];
        int2 b = off2[node0 + G1N - 1];
        s_start = a.x;
        s_n = b.x + b.y - a.x;
        s_ov = *ocur;
    }
    for (int i = tid; i < EMBED * HIDDEN; i += 256) sw2[i >> 5][i & 31] = W2[i];
    __syncthreads();
    const int start = s_start, n = s_n, ov = min(s_ov, OCAP);
    const bool fit = (n <= G1CAP);
    if (fit) for (int i = tid; i < n; i += 256) sc[i] = csr[start + i];
    __syncthreads();

    const int node = node0 + (tid >> 3);
    const int og = tid & 7;
    float d = dis[node];
    float d2 = d * d;
    float4 self = *(const float4*)(h + (size_t)node * HIDDEN + og * 4);
    float4 bv = *(const float4*)(b1 + og * 4);
    float4 acc = make_float4(0.f, 0.f, 0.f, 0.f);

    int2 o = off2[node];
    for (int j = 0; j < o.y; ++j) {
        int2 v = fit ? sc[o.x - start + j] : csr[o.x + j];
        float w = __int_as_float(v.y);
        const float4 hv = *(const float4*)(h + (size_t)v.x * HIDDEN + og * 4);
        acc.x += hv.x * w; acc.y += hv.y * w; acc.z += hv.z * w; acc.w += hv.w * w;
    }
    float4 res = make_float4(acc.x * d + self.x * d2 + bv.x,
                             acc.y * d + self.y * d2 + bv.y,
                             acc.z * d + self.z * d2 + bv.z,
                             acc.w * d + self.w * d2 + bv.w);
    if (ov > 0) {  // exact overflow fallback (never taken in practice)
        for (int q = 0; q < ov; ++q) {
            int4 t = olist[q];
            if (t.y == node) {
                float w = dis[t.x] * __int_as_float(t.z) * d;
                const float4 hv = *(const float4*)(h + (size_t)t.x * HIDDEN + og * 4);
                res.x += hv.x * w; res.y += hv.y * w;
                res.z += hv.z * w; res.w += hv.w * w;
            }
        }
    }
    // relu + stage
    *(float4*)&sout[tid >> 3][og * 4] =
        make_float4(fmaxf(res.x, 0.f), fmaxf(res.y, 0.f),
                    fmaxf(res.z, 0.f), fmaxf(res.w, 0.f));
    __syncthreads();
    // h2 = relu(out1) @ W2^T : 32 nodes x 16 feats, 2 per thread
    const int n2 = tid >> 3;
    const int f2 = (tid & 7) * 2;
    float a0 = 0.f, a1 = 0.f;
#pragma unroll
    for (int k = 0; k < HIDDEN; ++k) {
        float r = sout[n2][k];
        a0 += r * sw2[f2][k];
        a1 += r * sw2[f2 + 1][k];
    }
    h2[(size_t)(node0 + n2) * EMBED + f2] = a0;
    h2[(size_t)(node0 + n2) * EMBED + f2 + 1] = a1;
}

// ---- layer 2 gather (+ in-kernel overflow): out = gcn2(h2) ----
__global__ __launch_bounds__(256) void k_gather2(
        const int2* __restrict__ off2, const int2* __restrict__ csr,
        const float* __restrict__ h2, const float* __restrict__ dis,
        const float* __restrict__ b2, const int* __restrict__ ocur,
        const int4* __restrict__ olist, float* __restrict__ out) {
    __shared__ int2 sc[G2CAP];
    __shared__ int s_start, s_n, s_ov;
    const int tid = threadIdx.x;
    const int node0 = blockIdx.x * G2N;
    const int lastn = min(node0 + G2N, N_NODES) - 1;
    if (tid == 0) {
        int2 a = off2[node0];
        int2 b = off2[lastn];
        s_start = a.x;
        s_n = b.x + b.y - a.x;
        s_ov = *ocur;
    }
    __syncthreads();
    const int start = s_start, n = s_n, ov = min(s_ov, OCAP);
    const bool fit = (n <= G2CAP);
    if (fit) for (int i = tid; i < n; i += 256) sc[i] = csr[start + i];
    __syncthreads();

    const int node = node0 + (tid >> 2);
    const int og = tid & 3;
    if (node >= N_NODES) return;
    float d = dis[node];
    float d2 = d * d;
    float4 self = *(const float4*)(h2 + (size_t)node * EMBED + og * 4);
    float4 bv = *(const float4*)(b2 + og * 4);
    float4 acc = make_float4(0.f, 0.f, 0.f, 0.f);

    int2 o = off2[node];
    for (int j = 0; j < o.y; ++j) {
        int2 v = fit ? sc[o.x - start + j] : csr[o.x + j];
        float w = __int_as_float(v.y);
        const float4 hv = *(const float4*)(h2 + (size_t)v.x * EMBED + og * 4);
        acc.x += hv.x * w; acc.y += hv.y * w; acc.z += hv.z * w; acc.w += hv.w * w;
    }
    float4 res = make_float4(acc.x * d + self.x * d2 + bv.x,
                             acc.y * d + self.y * d2 + bv.y,
                             acc.z * d + self.z * d2 + bv.z,
                             acc.w * d + self.w * d2 + bv.w);
    if (ov > 0) {  // exact overflow fallback
        for (int q = 0; q < ov; ++q) {
            int4 t = olist[q];
            if (t.y == node) {
                float w = dis[t.x] * __int_as_float(t.z) * d;
                const float4 hv = *(const float4*)(h2 + (size_t)t.x * EMBED + og * 4);
                res.x += hv.x * w; res.y += hv.y * w;
                res.z += hv.z * w; res.w += hv.w * w;
            }
        }
    }
    *(float4*)(out + (size_t)node * EMBED + og * 4) = res;
}

extern "C" void kernel_launch(void* const* d_in, const int* in_sizes, int n_in,
                              void* d_out, int out_size, void* d_ws, size_t ws_size,
                              hipStream_t stream) {
    const float* x  = (const float*)d_in[0];
    const int*   ei = (const int*)d_in[1];  // [2, E] int32
    const float* ew = (const float*)d_in[2];
    const float* W1 = (const float*)d_in[3];
    const float* b1 = (const float*)d_in[4];
    const float* W2 = (const float*)d_in[5];
    const float* b2 = (const float*)d_in[6];
    float* out = (float*)d_out;

    const int* row = ei;            // source
    const int* col = ei + N_EDGES;  // target

    // ws layout:
    // off2[N] int2 | binned[NBIN*CAPB] int2 | deg[N] f32 | binTot[784] int |
    // offm[PBLK*OMS] int | ocur[4] int | olist[OCAP] int4 |
    // big: chunks[PBLK*PEPB] int2  ALIASES  h[32N] + h2[16N]
    int2*  off2   = (int2*)d_ws;
    int2*  binned = off2 + N_NODES;
    float* deg    = (float*)(binned + (size_t)NBIN * CAPB);
    int*   binTot = (int*)(deg + N_NODES);
    int*   offm   = binTot + 784;
    int*   ocur   = offm + (size_t)PBLK * OMS;
    int4*  olist  = (int4*)(ocur + 4);
    void*  big    = (void*)(olist + OCAP);
    int2*  chunks = (int2*)big;
    float* h      = (float*)big;               // alias: chunks dead before gemm1
    float* h2     = h + (size_t)N_NODES * HIDDEN;

    const int B = 256;
    const int gN = (N_NODES + B - 1) / B;
    const int gO = (OCAP + B - 1) / B;

    k_part<<<PBLK, B, 0, stream>>>(row, col, ew, offm, chunks, ocur);
    k_build<<<NBIN, B, 0, stream>>>(offm, chunks, binned, deg, off2, binTot, ocur, olist);
    k_degover<<<gO, B, 0, stream>>>(ocur, olist, deg);
    k_dis<<<gN, B, 0, stream>>>(deg);
    k_wnorm<<<NBIN, B, 0, stream>>>(binTot, binned, deg);
    k_gemm1<<<(N_NODES + GR - 1) / GR, B, 0, stream>>>(x, W1, h);
    k_gather1<<<N_NODES / G1N, B, 0, stream>>>(off2, binned, h, deg, b1, W2, ocur, olist, h2);
    k_gather2<<<(N_NODES + G2N - 1) / G2N, B, 0, stream>>>(off2, binned, h2, deg, b2, ocur, olist, out);
}

// Round 25
// 290.458 us; speedup vs baseline: 1.2817x; 1.2817x over previous
//
#include <hip/hip_runtime.h>
#include <hip/hip_bf16.h>

#define N_NODES 100000
#define N_EDGES 3200000
#define FEAT 256
#define HIDDEN 32
#define EMBED 16
#define NPB 128                                // nodes per bin
#define NBIN ((N_NODES + NPB - 1) / NPB)       // 782
#define CAPB 4608                              // bin capacity (mean 4096 + 8 sigma)
#define OCAP 8192                              // overflow list capacity
#define GR 128                                 // gemm1 tile rows
#define G1N 32                                 // nodes per gather1 block
#define G1CAP 2048                             // LDS entries
#define G2N 64                                 // nodes per gather2 block
#define G2CAP 3072                             // LDS entries
#define PEPB 3072                              // edges per partition block
#define PBLK ((N_EDGES + PEPB - 1) / PEPB)     // 1042
#define OMS 784                                // offm row stride (782 bins + sentinel + pad)
#define RPT 5                                  // runs per thread in k_build (5*256 >= 1042)
#define NSK (NPB * 8)                          // sub-keys: node x 8 src-tiles

// ---------------- pass 1: per-block bin-grouped chunk + offset row ----------
__global__ __launch_bounds__(256, 4) void k_part(
        const int* __restrict__ row, const int* __restrict__ col,
        const float* __restrict__ ew, int* __restrict__ offm,
        int2* __restrict__ chunks, int* __restrict__ ocur) {
    __shared__ int2 sed[PEPB];                 // 24576 B staged edges (grouped)
    __shared__ int shist[NBIN];                // counts -> local excl offsets
    __shared__ int scur[NBIN];                 // scan scratch, then cursors
    const int tid = threadIdx.x;
    const int blk = blockIdx.x;
    const int e0 = blk * PEPB;
    const int ne = min(PEPB, N_EDGES - e0);
    if (blk == 0 && tid == 0) *ocur = 0;

    for (int i = tid; i < NBIN; i += 256) shist[i] = 0;
    __syncthreads();
    for (int i = tid; i < ne; i += 256) atomicAdd(&shist[col[e0 + i] >> 7], 1);
    __syncthreads();
    int l[4];
    int s = 0;
#pragma unroll
    for (int k = 0; k < 4; ++k) {
        int b = tid * 4 + k;
        l[k] = (b < NBIN) ? shist[b] : 0;
        s += l[k];
    }
    scur[tid] = s;
    __syncthreads();
    for (int d = 1; d < 256; d <<= 1) {
        int t = (tid >= d) ? scur[tid - d] : 0;
        __syncthreads();
        scur[tid] += t;
        __syncthreads();
    }
    int ex = scur[tid] - s;
    __syncthreads();
#pragma unroll
    for (int k = 0; k < 4; ++k) {
        int b = tid * 4 + k;
        if (b < NBIN) {
            shist[b] = ex;
            scur[b] = ex;
            ex += l[k];
        }
    }
    __syncthreads();
    for (int b = tid; b < NBIN; b += 256) offm[blk * OMS + b] = shist[b];
    if (tid == 0) offm[blk * OMS + NBIN] = ne;
    for (int i = tid; i < ne; i += 256) {
        int e = e0 + i;
        int c = col[e];
        int b = c >> 7;
        int p = atomicAdd(&scur[b], 1);        // LDS atomic
        sed[p] = make_int2(((c & (NPB - 1)) << 17) | row[e], __float_as_int(ew[e]));
    }
    __syncthreads();
    for (int i = tid; i < ne; i += 256) chunks[(size_t)blk * PEPB + i] = sed[i];
}

// ---------------- pass 2: per-bin gather-from-chunks + group + deg + off2 ----
__global__ __launch_bounds__(256) void k_build(
        const int* __restrict__ offm, const int2* __restrict__ chunks,
        int2* __restrict__ binned, float* __restrict__ deg,
        int2* __restrict__ off2, int* __restrict__ binTot,
        int* __restrict__ ocur, int4* __restrict__ olist) {
    __shared__ int2 se[CAPB];                      // 36864 B
    __shared__ int scnt[NSK], scur2[NSK];          // 2 x 4096 B
    __shared__ float sdeg[NPB];
    __shared__ int spart[256];
    const int bin = blockIdx.x, tid = threadIdx.x;
    const size_t base = (size_t)bin * CAPB;

    for (int i = tid; i < NSK; i += 256) scnt[i] = 0;
    for (int i = tid; i < NPB; i += 256) sdeg[i] = 0.f;
    int st[RPT], ln[RPT];
    int s = 0;
#pragma unroll
    for (int r = 0; r < RPT; ++r) {
        int k = tid * RPT + r;
        int a = 0, b2 = 0;
        if (k < PBLK) {
            a = offm[k * OMS + bin];
            b2 = offm[k * OMS + bin + 1];
        }
        st[r] = a;
        ln[r] = b2 - a;
        s += ln[r];
    }
    spart[tid] = s;
    __syncthreads();
    for (int d = 1; d < 256; d <<= 1) {
        int t = (tid >= d) ? spart[tid - d] : 0;
        __syncthreads();
        spart[tid] += t;
        __syncthreads();
    }
    int ex = spart[tid] - s;
    const int nTot = spart[255];
    const int n = min(nTot, CAPB);
    int dp = ex;
#pragma unroll
    for (int r = 0; r < RPT; ++r) {
        int k = tid * RPT + r;
        if (k < PBLK) {
            const int2* src = chunks + (size_t)k * PEPB + st[r];
            for (int j = 0; j < ln[r]; ++j) {
                int2 v = src[j];
                int lc = v.x >> 17;
                int dst = dp + j;
                if (dst < CAPB) {
                    se[dst] = v;
                    atomicAdd(&scnt[lc * 8 + ((v.x & 0x1FFFF) >> 14)], 1);
                    atomicAdd(&sdeg[lc], __int_as_float(v.y));
                } else {
                    int q = atomicAdd(ocur, 1);
                    if (q < OCAP)
                        olist[q] = make_int4(v.x & 0x1FFFF, bin * NPB + lc, v.y, 0);
                }
            }
            dp += ln[r];
        }
    }
    __syncthreads();
    int l0 = scnt[tid * 4], l1 = scnt[tid * 4 + 1],
        l2 = scnt[tid * 4 + 2], l3 = scnt[tid * 4 + 3];
    int s2 = l0 + l1 + l2 + l3;
    spart[tid] = s2;
    __syncthreads();
    for (int d = 1; d < 256; d <<= 1) {
        int t = (tid >= d) ? spart[tid - d] : 0;
        __syncthreads();
        spart[tid] += t;
        __syncthreads();
    }
    int ex2 = spart[tid] - s2;
    scnt[tid * 4] = ex2;
    scnt[tid * 4 + 1] = ex2 + l0;
    scnt[tid * 4 + 2] = ex2 + l0 + l1;
    scnt[tid * 4 + 3] = ex2 + l0 + l1 + l2;
    __syncthreads();
    for (int i = tid; i < NSK; i += 256) scur2[i] = scnt[i];
    __syncthreads();
    if (tid < NPB) {
        int node = bin * NPB + tid;
        if (node < N_NODES) {
            int stn = scnt[tid * 8];
            int en = (tid == NPB - 1) ? n : scnt[(tid + 1) * 8];
            off2[node] = make_int2((int)base + stn, en - stn);
            deg[node] = sdeg[tid] + 1.0f;  // + self loop
        }
    }
    if (tid == 0) binTot[bin] = n;
    __syncthreads();
    for (int i = tid; i < n; i += 256) {
        int2 v = se[i];
        int lc = v.x >> 17, src2 = v.x & 0x1FFFF;
        int p = atomicAdd(&scur2[lc * 8 + (src2 >> 14)], 1);  // LDS atomic
        binned[base + p] = make_int2(src2, v.y);
    }
}

__global__ void k_degover(const int* __restrict__ ocur, const int4* __restrict__ olist,
                          float* __restrict__ deg) {
    int p = blockIdx.x * blockDim.x + threadIdx.x;
    int n = min(*ocur, OCAP);
    if (p < n) { int4 t = olist[p]; unsafeAtomicAdd(&deg[t.y], __int_as_float(t.z)); }
}

__global__ void k_dis(float* __restrict__ deg) {
    int i = blockIdx.x * blockDim.x + threadIdx.x;
    if (i < N_NODES) {
        float d = deg[i];
        deg[i] = (d > 0.0f) ? rsqrtf(d) : 0.0f;
    }
}

// ---------------- fold dis[src] into csr weights in-place ----------------
__global__ void k_wnorm(const int* __restrict__ binTot, int2* __restrict__ csr,
                        const float* __restrict__ dis) {
    int bin = blockIdx.x;
    int n = binTot[bin];
    size_t base = (size_t)bin * CAPB;
    for (int i = threadIdx.x; i < n; i += 256) {
        int2 v = csr[base + i];
        float w = __int_as_float(v.y) * dis[v.x];
        csr[base + i] = make_int2(v.x, __float_as_int(w));
    }
}

// ---------------- layer 1 GEMM: h = x @ W1^T, software-pipelined (R19) ------
__global__ __launch_bounds__(256) void k_gemm1(
        const float* __restrict__ x, const float* __restrict__ W1,
        float* __restrict__ h) {
    __shared__ float sx[GR][36];       // 18432 B
    __shared__ float sw[HIDDEN][260];  // 33280 B

    const int tid = threadIdx.x;
    const size_t base = (size_t)blockIdx.x * GR;
    const float4* x4 = (const float4*)x;
    const float4* w4 = (const float4*)W1;
    const int rs = tid >> 3;
    const int ks = tid & 7;

    for (int i = tid; i < HIDDEN * 64; i += 256) {
        int f = i >> 6, kq = i & 63;
        *(float4*)&sw[f][kq * 4] = w4[f * 64 + kq];
    }
    float4 stg[4];
#pragma unroll
    for (int m = 0; m < 4; ++m) {
        int rr = rs + 32 * m;
        stg[m] = make_float4(0.f, 0.f, 0.f, 0.f);
        if (base + rr < N_NODES) stg[m] = x4[(base + rr) * 64 + ks];
    }
#pragma unroll
    for (int m = 0; m < 4; ++m) *(float4*)&sx[rs + 32 * m][ks * 4] = stg[m];
    __syncthreads();

    const int r0 = tid >> 3;
    const int c0 = tid & 7;
    float acc[4][4] = {};

    for (int p = 0; p < 8; ++p) {
        if (p < 7) {
#pragma unroll
            for (int m = 0; m < 4; ++m) {
                int rr = rs + 32 * m;
                stg[m] = make_float4(0.f, 0.f, 0.f, 0.f);
                if (base + rr < N_NODES) stg[m] = x4[(base + rr) * 64 + (p + 1) * 8 + ks];
            }
        }
#pragma unroll
        for (int kq = 0; kq < 8; ++kq) {
            float4 xa[4], wv[4];
#pragma unroll
            for (int m = 0; m < 4; ++m) xa[m] = *(const float4*)&sx[r0 + 32 * m][kq * 4];
#pragma unroll
            for (int j = 0; j < 4; ++j) wv[j] = *(const float4*)&sw[c0 + 8 * j][(p * 8 + kq) * 4];
#pragma unroll
            for (int m = 0; m < 4; ++m)
#pragma unroll
                for (int j = 0; j < 4; ++j)
                    acc[m][j] += xa[m].x * wv[j].x + xa[m].y * wv[j].y +
                                 xa[m].z * wv[j].z + xa[m].w * wv[j].w;
        }
        __syncthreads();
        if (p < 7) {
#pragma unroll
            for (int m = 0; m < 4; ++m) *(float4*)&sx[rs + 32 * m][ks * 4] = stg[m];
            __syncthreads();
        }
    }

#pragma unroll
    for (int m = 0; m < 4; ++m) {
        size_t r = base + r0 + 32 * m;
        if (r < N_NODES) {
#pragma unroll
            for (int j = 0; j < 4; ++j) h[r * HIDDEN + c0 + 8 * j] = acc[m][j];
        }
    }
}

// ---- FUSED layer-1 gather + gemm2: h2 = relu(gcn1(h)) @ W2^T ----
__global__ __launch_bounds__(256) void k_gather1(
        const int2* __restrict__ off2, const int2* __restrict__ csr,
        const float* __restrict__ h, const float* __restrict__ dis,
        const float* __restrict__ b1, const float* __restrict__ W2,
        const int* __restrict__ ocur, const int4* __restrict__ olist,
        float* __restrict__ h2) {
    __shared__ int2 sc[G1CAP];                 // 16384 B csr window
    __shared__ float sw2[EMBED][HIDDEN + 1];   //  2112 B (stride 33: bank = f+k)
    __shared__ float sout[G1N][HIDDEN + 1];    //  4224 B relu(out1)
    __shared__ int s_start, s_n, s_ov;
    const int tid = threadIdx.x;
    const int node0 = blockIdx.x * G1N;        // 100000 = 32*3125 exact
    if (tid == 0) {
        int2 a = off2[node0];
        int2 b = off2[node0 + G1N - 1];
        s_start = a.x;
        s_n = b.x + b.y - a.x;
        s_ov = *ocur;
    }
    for (int i = tid; i < EMBED * HIDDEN; i += 256) sw2[i >> 5][i & 31] = W2[i];
    __syncthreads();
    const int start = s_start, n = s_n, ov = min(s_ov, OCAP);
    const bool fit = (n <= G1CAP);
    if (fit) for (int i = tid; i < n; i += 256) sc[i] = csr[start + i];
    __syncthreads();

    const int node = node0 + (tid >> 3);
    const int og = tid & 7;
    float d = dis[node];
    float d2 = d * d;
    float4 self = *(const float4*)(h + (size_t)node * HIDDEN + og * 4);
    float4 bv = *(const float4*)(b1 + og * 4);
    float4 acc = make_float4(0.f, 0.f, 0.f, 0.f);

    int2 o = off2[node];
    for (int j = 0; j < o.y; ++j) {
        int2 v = fit ? sc[o.x - start + j] : csr[o.x + j];
        float w = __int_as_float(v.y);
        const float4 hv = *(const float4*)(h + (size_t)v.x * HIDDEN + og * 4);
        acc.x += hv.x * w; acc.y += hv.y * w; acc.z += hv.z * w; acc.w += hv.w * w;
    }
    float4 res = make_float4(acc.x * d + self.x * d2 + bv.x,
                             acc.y * d + self.y * d2 + bv.y,
                             acc.z * d + self.z * d2 + bv.z,
                             acc.w * d + self.w * d2 + bv.w);
    if (ov > 0) {  // exact overflow fallback (never taken in practice)
        for (int q = 0; q < ov; ++q) {
            int4 t = olist[q];
            if (t.y == node) {
                float w = dis[t.x] * __int_as_float(t.z) * d;
                const float4 hv = *(const float4*)(h + (size_t)t.x * HIDDEN + og * 4);
                res.x += hv.x * w; res.y += hv.y * w;
                res.z += hv.z * w; res.w += hv.w * w;
            }
        }
    }
    // relu + stage
    *(float4*)&sout[tid >> 3][og * 4] =
        make_float4(fmaxf(res.x, 0.f), fmaxf(res.y, 0.f),
                    fmaxf(res.z, 0.f), fmaxf(res.w, 0.f));
    __syncthreads();
    // h2 = relu(out1) @ W2^T : 32 nodes x 16 feats, 2 per thread
    const int n2 = tid >> 3;
    const int f2 = (tid & 7) * 2;
    float a0 = 0.f, a1 = 0.f;
#pragma unroll
    for (int k = 0; k < HIDDEN; ++k) {
        float r = sout[n2][k];
        a0 += r * sw2[f2][k];
        a1 += r * sw2[f2 + 1][k];
    }
    h2[(size_t)(node0 + n2) * EMBED + f2] = a0;
    h2[(size_t)(node0 + n2) * EMBED + f2 + 1] = a1;
}

// ---- layer 2 gather (+ in-kernel overflow): out = gcn2(h2) ----
__global__ __launch_bounds__(256) void k_gather2(
        const int2* __restrict__ off2, const int2* __restrict__ csr,
        const float* __restrict__ h2, const float* __restrict__ dis,
        const float* __restrict__ b2, const int* __restrict__ ocur,
        const int4* __restrict__ olist, float* __restrict__ out) {
    __shared__ int2 sc[G2CAP];
    __shared__ int s_start, s_n, s_ov;
    const int tid = threadIdx.x;
    const int node0 = blockIdx.x * G2N;
    const int lastn = min(node0 + G2N, N_NODES) - 1;
    if (tid == 0) {
        int2 a = off2[node0];
        int2 b = off2[lastn];
        s_start = a.x;
        s_n = b.x + b.y - a.x;
        s_ov = *ocur;
    }
    __syncthreads();
    const int start = s_start, n = s_n, ov = min(s_ov, OCAP);
    const bool fit = (n <= G2CAP);
    if (fit) for (int i = tid; i < n; i += 256) sc[i] = csr[start + i];
    __syncthreads();

    const int node = node0 + (tid >> 2);
    const int og = tid & 3;
    if (node >= N_NODES) return;
    float d = dis[node];
    float d2 = d * d;
    float4 self = *(const float4*)(h2 + (size_t)node * EMBED + og * 4);
    float4 bv = *(const float4*)(b2 + og * 4);
    float4 acc = make_float4(0.f, 0.f, 0.f, 0.f);

    int2 o = off2[node];
    for (int j = 0; j < o.y; ++j) {
        int2 v = fit ? sc[o.x - start + j] : csr[o.x + j];
        float w = __int_as_float(v.y);
        const float4 hv = *(const float4*)(h2 + (size_t)v.x * EMBED + og * 4);
        acc.x += hv.x * w; acc.y += hv.y * w; acc.z += hv.z * w; acc.w += hv.w * w;
    }
    float4 res = make_float4(acc.x * d + self.x * d2 + bv.x,
                             acc.y * d + self.y * d2 + bv.y,
                             acc.z * d + self.z * d2 + bv.z,
                             acc.w * d + self.w * d2 + bv.w);
    if (ov > 0) {  // exact overflow fallback
        for (int q = 0; q < ov; ++q) {
            int4 t = olist[q];
            if (t.y == node) {
                float w = dis[t.x] * __int_as_float(t.z) * d;
                const float4 hv = *(const float4*)(h2 + (size_t)t.x * EMBED + og * 4);
                res.x += hv.x * w; res.y += hv.y * w;
                res.z += hv.z * w; res.w += hv.w * w;
            }
        }
    }
    *(float4*)(out + (size_t)node * EMBED + og * 4) = res;
}

extern "C" void kernel_launch(void* const* d_in, const int* in_sizes, int n_in,
                              void* d_out, int out_size, void* d_ws, size_t ws_size,
                              hipStream_t stream) {
    const float* x  = (const float*)d_in[0];
    const int*   ei = (const int*)d_in[1];  // [2, E] int32
    const float* ew = (const float*)d_in[2];
    const float* W1 = (const float*)d_in[3];
    const float* b1 = (const float*)d_in[4];
    const float* W2 = (const float*)d_in[5];
    const float* b2 = (const float*)d_in[6];
    float* out = (float*)d_out;

    const int* row = ei;            // source
    const int* col = ei + N_EDGES;  // target

    // ws layout:
    // off2[N] int2 | binned[NBIN*CAPB] int2 | deg[N] f32 | binTot[784] int |
    // offm[PBLK*OMS] int | ocur[4] int | olist[OCAP] int4 |
    // big: chunks[PBLK*PEPB] int2  ALIASES  h[32N] + h2[16N]
    int2*  off2   = (int2*)d_ws;
    int2*  binned = off2 + N_NODES;
    float* deg    = (float*)(binned + (size_t)NBIN * CAPB);
    int*   binTot = (int*)(deg + N_NODES);
    int*   offm   = binTot + 784;
    int*   ocur   = offm + (size_t)PBLK * OMS;
    int4*  olist  = (int4*)(ocur + 4);
    void*  big    = (void*)(olist + OCAP);
    int2*  chunks = (int2*)big;
    float* h      = (float*)big;               // alias: chunks dead before gemm1
    float* h2     = h + (size_t)N_NODES * HIDDEN;

    const int B = 256;
    const int gN = (N_NODES + B - 1) / B;
    const int gO = (OCAP + B - 1) / B;

    k_part<<<PBLK, B, 0, stream>>>(row, col, ew, offm, chunks, ocur);
    k_build<<<NBIN, B, 0, stream>>>(offm, chunks, binned, deg, off2, binTot, ocur, olist);
    k_degover<<<gO, B, 0, stream>>>(ocur, olist, deg);
    k_dis<<<gN, B, 0, stream>>>(deg);
    k_wnorm<<<NBIN, B, 0, stream>>>(binTot, binned, deg);
    k_gemm1<<<(N_NODES + GR - 1) / GR, B, 0, stream>>>(x, W1, h);
    k_gather1<<<N_NODES / G1N, B, 0, stream>>>(off2, binned, h, deg, b1, W2, ocur, olist, h2);
    k_gather2<<<(N_NODES + G2N - 1) / G2N, B, 0, stream>>>(off2, binned, h2, deg, b2, ocur, olist, out);
}

// Round 26
// 271.127 us; speedup vs baseline: 1.3731x; 1.0713x over previous
//
#include <hip/hip_runtime.h>
#include <hip/hip_bf16.h>

#define N_NODES 100000
#define N_EDGES 3200000
#define FEAT 256
#define HIDDEN 32
#define EMBED 16
#define NPB 128                                // nodes per bin
#define NBIN ((N_NODES + NPB - 1) / NPB)       // 782
#define CAPB 4608                              // bin capacity (mean 4096 + 8 sigma)
#define OCAP 8192                              // overflow list capacity
#define GR 128                                 // gemm1 tile rows
#define G1N 32                                 // nodes per gather1 block
#define G1CAP 2048                             // LDS entries
#define G2N 64                                 // nodes per gather2 block
#define G2CAP 3072                             // LDS entries
#define PEPB 3072                              // edges per partition block
#define PBLK ((N_EDGES + PEPB - 1) / PEPB)     // 1042
#define OMS 784                                // offm row stride (782 bins + sentinel + pad)
#define RPT 5                                  // runs per thread in k_build (5*256 >= 1042)
#define NSK (NPB * 8)                          // sub-keys: node x 8 src-tiles

// ---------------- pass 1: per-block bin-grouped chunk + offset row ----------
__global__ __launch_bounds__(256, 4) void k_part(
        const int* __restrict__ row, const int* __restrict__ col,
        const float* __restrict__ ew, int* __restrict__ offm,
        int2* __restrict__ chunks, int* __restrict__ ocur) {
    __shared__ int2 sed[PEPB];                 // 24576 B staged edges (grouped)
    __shared__ int shist[NBIN];                // counts -> local excl offsets
    __shared__ int scur[NBIN];                 // scan scratch, then cursors
    const int tid = threadIdx.x;
    const int blk = blockIdx.x;
    const int e0 = blk * PEPB;
    const int ne = min(PEPB, N_EDGES - e0);
    if (blk == 0 && tid == 0) *ocur = 0;

    for (int i = tid; i < NBIN; i += 256) shist[i] = 0;
    __syncthreads();
    for (int i = tid; i < ne; i += 256) atomicAdd(&shist[col[e0 + i] >> 7], 1);
    __syncthreads();
    int l[4];
    int s = 0;
#pragma unroll
    for (int k = 0; k < 4; ++k) {
        int b = tid * 4 + k;
        l[k] = (b < NBIN) ? shist[b] : 0;
        s += l[k];
    }
    scur[tid] = s;
    __syncthreads();
    for (int d = 1; d < 256; d <<= 1) {
        int t = (tid >= d) ? scur[tid - d] : 0;
        __syncthreads();
        scur[tid] += t;
        __syncthreads();
    }
    int ex = scur[tid] - s;
    __syncthreads();
#pragma unroll
    for (int k = 0; k < 4; ++k) {
        int b = tid * 4 + k;
        if (b < NBIN) {
            shist[b] = ex;
            scur[b] = ex;
            ex += l[k];
        }
    }
    __syncthreads();
    for (int b = tid; b < NBIN; b += 256) offm[blk * OMS + b] = shist[b];
    if (tid == 0) offm[blk * OMS + NBIN] = ne;
    for (int i = tid; i < ne; i += 256) {
        int e = e0 + i;
        int c = col[e];
        int b = c >> 7;
        int p = atomicAdd(&scur[b], 1);        // LDS atomic
        sed[p] = make_int2(((c & (NPB - 1)) << 17) | row[e], __float_as_int(ew[e]));
    }
    __syncthreads();
    for (int i = tid; i < ne; i += 256) chunks[(size_t)blk * PEPB + i] = sed[i];
}

// ---------------- pass 2: per-bin gather-from-chunks + group + deg + off2 ----
__global__ __launch_bounds__(256) void k_build(
        const int* __restrict__ offm, const int2* __restrict__ chunks,
        int2* __restrict__ binned, float* __restrict__ deg,
        int2* __restrict__ off2, int* __restrict__ ocur, int4* __restrict__ olist) {
    __shared__ int2 se[CAPB];                      // 36864 B
    __shared__ int scnt[NSK], scur2[NSK];          // 2 x 4096 B
    __shared__ float sdeg[NPB];
    __shared__ int spart[256];
    const int bin = blockIdx.x, tid = threadIdx.x;
    const size_t base = (size_t)bin * CAPB;

    for (int i = tid; i < NSK; i += 256) scnt[i] = 0;
    for (int i = tid; i < NPB; i += 256) sdeg[i] = 0.f;
    int st[RPT], ln[RPT];
    int s = 0;
#pragma unroll
    for (int r = 0; r < RPT; ++r) {
        int k = tid * RPT + r;
        int a = 0, b2 = 0;
        if (k < PBLK) {
            a = offm[k * OMS + bin];
            b2 = offm[k * OMS + bin + 1];
        }
        st[r] = a;
        ln[r] = b2 - a;
        s += ln[r];
    }
    spart[tid] = s;
    __syncthreads();
    for (int d = 1; d < 256; d <<= 1) {
        int t = (tid >= d) ? spart[tid - d] : 0;
        __syncthreads();
        spart[tid] += t;
        __syncthreads();
    }
    int ex = spart[tid] - s;
    const int nTot = spart[255];
    const int n = min(nTot, CAPB);
    int dp = ex;
#pragma unroll
    for (int r = 0; r < RPT; ++r) {
        int k = tid * RPT + r;
        if (k < PBLK) {
            const int2* src = chunks + (size_t)k * PEPB + st[r];
            for (int j = 0; j < ln[r]; ++j) {
                int2 v = src[j];
                int lc = v.x >> 17;
                int dst = dp + j;
                if (dst < CAPB) {
                    se[dst] = v;
                    atomicAdd(&scnt[lc * 8 + ((v.x & 0x1FFFF) >> 14)], 1);
                    atomicAdd(&sdeg[lc], __int_as_float(v.y));
                } else {
                    int q = atomicAdd(ocur, 1);
                    if (q < OCAP)
                        olist[q] = make_int4(v.x & 0x1FFFF, bin * NPB + lc, v.y, 0);
                }
            }
            dp += ln[r];
        }
    }
    __syncthreads();
    int l0 = scnt[tid * 4], l1 = scnt[tid * 4 + 1],
        l2 = scnt[tid * 4 + 2], l3 = scnt[tid * 4 + 3];
    int s2 = l0 + l1 + l2 + l3;
    spart[tid] = s2;
    __syncthreads();
    for (int d = 1; d < 256; d <<= 1) {
        int t = (tid >= d) ? spart[tid - d] : 0;
        __syncthreads();
        spart[tid] += t;
        __syncthreads();
    }
    int ex2 = spart[tid] - s2;
    scnt[tid * 4] = ex2;
    scnt[tid * 4 + 1] = ex2 + l0;
    scnt[tid * 4 + 2] = ex2 + l0 + l1;
    scnt[tid * 4 + 3] = ex2 + l0 + l1 + l2;
    __syncthreads();
    for (int i = tid; i < NSK; i += 256) scur2[i] = scnt[i];
    __syncthreads();
    if (tid < NPB) {
        int node = bin * NPB + tid;
        if (node < N_NODES) {
            int stn = scnt[tid * 8];
            int en = (tid == NPB - 1) ? n : scnt[(tid + 1) * 8];
            off2[node] = make_int2((int)base + stn, en - stn);
            deg[node] = sdeg[tid] + 1.0f;  // + self loop
        }
    }
    __syncthreads();
    for (int i = tid; i < n; i += 256) {
        int2 v = se[i];
        int lc = v.x >> 17, src2 = v.x & 0x1FFFF;
        int p = atomicAdd(&scur2[lc * 8 + (src2 >> 14)], 1);  // LDS atomic
        binned[base + p] = make_int2(src2, v.y);              // {src, raw ew}
    }
}

__global__ void k_degover(const int* __restrict__ ocur, const int4* __restrict__ olist,
                          float* __restrict__ deg) {
    int p = blockIdx.x * blockDim.x + threadIdx.x;
    int n = min(*ocur, OCAP);
    if (p < n) { int4 t = olist[p]; unsafeAtomicAdd(&deg[t.y], __int_as_float(t.z)); }
}

__global__ void k_dis(float* __restrict__ deg) {
    int i = blockIdx.x * blockDim.x + threadIdx.x;
    if (i < N_NODES) {
        float d = deg[i];
        deg[i] = (d > 0.0f) ? rsqrtf(d) : 0.0f;
    }
}

// ---------------- layer 1 GEMM: h' = (x @ W1^T) * dis, software-pipelined ---
// Writing h' = h*dis folds the dis[src] normalization into the existing h
// store: k_wnorm (51MB r/w pass over csr) is DELETED; gathers use raw ew.
__global__ __launch_bounds__(256) void k_gemm1(
        const float* __restrict__ x, const float* __restrict__ W1,
        const float* __restrict__ dis, float* __restrict__ h) {
    __shared__ float sx[GR][36];       // 18432 B
    __shared__ float sw[HIDDEN][260];  // 33280 B

    const int tid = threadIdx.x;
    const size_t base = (size_t)blockIdx.x * GR;
    const float4* x4 = (const float4*)x;
    const float4* w4 = (const float4*)W1;
    const int rs = tid >> 3;
    const int ks = tid & 7;

    for (int i = tid; i < HIDDEN * 64; i += 256) {
        int f = i >> 6, kq = i & 63;
        *(float4*)&sw[f][kq * 4] = w4[f * 64 + kq];
    }
    float4 stg[4];
#pragma unroll
    for (int m = 0; m < 4; ++m) {
        int rr = rs + 32 * m;
        stg[m] = make_float4(0.f, 0.f, 0.f, 0.f);
        if (base + rr < N_NODES) stg[m] = x4[(base + rr) * 64 + ks];
    }
#pragma unroll
    for (int m = 0; m < 4; ++m) *(float4*)&sx[rs + 32 * m][ks * 4] = stg[m];
    __syncthreads();

    const int r0 = tid >> 3;
    const int c0 = tid & 7;
    float acc[4][4] = {};

    for (int p = 0; p < 8; ++p) {
        if (p < 7) {
#pragma unroll
            for (int m = 0; m < 4; ++m) {
                int rr = rs + 32 * m;
                stg[m] = make_float4(0.f, 0.f, 0.f, 0.f);
                if (base + rr < N_NODES) stg[m] = x4[(base + rr) * 64 + (p + 1) * 8 + ks];
            }
        }
#pragma unroll
        for (int kq = 0; kq < 8; ++kq) {
            float4 xa[4], wv[4];
#pragma unroll
            for (int m = 0; m < 4; ++m) xa[m] = *(const float4*)&sx[r0 + 32 * m][kq * 4];
#pragma unroll
            for (int j = 0; j < 4; ++j) wv[j] = *(const float4*)&sw[c0 + 8 * j][(p * 8 + kq) * 4];
#pragma unroll
            for (int m = 0; m < 4; ++m)
#pragma unroll
                for (int j = 0; j < 4; ++j)
                    acc[m][j] += xa[m].x * wv[j].x + xa[m].y * wv[j].y +
                                 xa[m].z * wv[j].z + xa[m].w * wv[j].w;
        }
        __syncthreads();
        if (p < 7) {
#pragma unroll
            for (int m = 0; m < 4; ++m) *(float4*)&sx[rs + 32 * m][ks * 4] = stg[m];
            __syncthreads();
        }
    }

#pragma unroll
    for (int m = 0; m < 4; ++m) {
        size_t r = base + r0 + 32 * m;
        if (r < N_NODES) {
            float ds = dis[r];
#pragma unroll
            for (int j = 0; j < 4; ++j) h[r * HIDDEN + c0 + 8 * j] = acc[m][j] * ds;
        }
    }
}

// ---- FUSED layer-1 gather + gemm2 (h is pre-scaled h' = h*dis) ----
// out1[c] = d*(sum h'[src]*ew + h'[c]) + b1 ; writes h2' = h2*dis.
__global__ __launch_bounds__(256) void k_gather1(
        const int2* __restrict__ off2, const int2* __restrict__ csr,
        const float* __restrict__ h, const float* __restrict__ dis,
        const float* __restrict__ b1, const float* __restrict__ W2,
        const int* __restrict__ ocur, const int4* __restrict__ olist,
        float* __restrict__ h2) {
    __shared__ int2 sc[G1CAP];                 // 16384 B csr window
    __shared__ float sw2[EMBED][HIDDEN + 1];   //  2112 B (stride 33)
    __shared__ float sout[G1N][HIDDEN + 1];    //  4224 B relu(out1)
    __shared__ int s_start, s_n, s_ov;
    const int tid = threadIdx.x;
    const int node0 = blockIdx.x * G1N;        // 100000 = 32*3125 exact
    if (tid == 0) {
        int2 a = off2[node0];
        int2 b = off2[node0 + G1N - 1];
        s_start = a.x;
        s_n = b.x + b.y - a.x;
        s_ov = *ocur;
    }
    for (int i = tid; i < EMBED * HIDDEN; i += 256) sw2[i >> 5][i & 31] = W2[i];
    __syncthreads();
    const int start = s_start, n = s_n, ov = min(s_ov, OCAP);
    const bool fit = (n <= G1CAP);
    if (fit) for (int i = tid; i < n; i += 256) sc[i] = csr[start + i];
    __syncthreads();

    const int node = node0 + (tid >> 3);
    const int og = tid & 7;
    float d = dis[node];
    float4 self = *(const float4*)(h + (size_t)node * HIDDEN + og * 4);
    float4 bv = *(const float4*)(b1 + og * 4);
    float4 acc = make_float4(0.f, 0.f, 0.f, 0.f);

    int2 o = off2[node];
    for (int j = 0; j < o.y; ++j) {
        int2 v = fit ? sc[o.x - start + j] : csr[o.x + j];
        float w = __int_as_float(v.y);           // raw ew
        const float4 hv = *(const float4*)(h + (size_t)v.x * HIDDEN + og * 4);
        acc.x += hv.x * w; acc.y += hv.y * w; acc.z += hv.z * w; acc.w += hv.w * w;
    }
    float4 res = make_float4((acc.x + self.x) * d + bv.x,
                             (acc.y + self.y) * d + bv.y,
                             (acc.z + self.z) * d + bv.z,
                             (acc.w + self.w) * d + bv.w);
    if (ov > 0) {  // exact overflow fallback (never taken in practice)
        for (int q = 0; q < ov; ++q) {
            int4 t = olist[q];
            if (t.y == node) {
                float w = __int_as_float(t.z) * d;  // h' includes dis[src]
                const float4 hv = *(const float4*)(h + (size_t)t.x * HIDDEN + og * 4);
                res.x += hv.x * w; res.y += hv.y * w;
                res.z += hv.z * w; res.w += hv.w * w;
            }
        }
    }
    // relu + stage
    *(float4*)&sout[tid >> 3][og * 4] =
        make_float4(fmaxf(res.x, 0.f), fmaxf(res.y, 0.f),
                    fmaxf(res.z, 0.f), fmaxf(res.w, 0.f));
    __syncthreads();
    // h2' = (relu(out1) @ W2^T) * dis : 32 nodes x 16 feats, 2 per thread
    const int n2 = tid >> 3;
    const int f2 = (tid & 7) * 2;
    float a0 = 0.f, a1 = 0.f;
#pragma unroll
    for (int k = 0; k < HIDDEN; ++k) {
        float r = sout[n2][k];
        a0 += r * sw2[f2][k];
        a1 += r * sw2[f2 + 1][k];
    }
    h2[(size_t)(node0 + n2) * EMBED + f2] = a0 * d;
    h2[(size_t)(node0 + n2) * EMBED + f2 + 1] = a1 * d;
}

// ---- layer 2 gather (h2 is pre-scaled h2' = h2*dis): out = gcn2 ----
__global__ __launch_bounds__(256) void k_gather2(
        const int2* __restrict__ off2, const int2* __restrict__ csr,
        const float* __restrict__ h2, const float* __restrict__ dis,
        const float* __restrict__ b2, const int* __restrict__ ocur,
        const int4* __restrict__ olist, float* __restrict__ out) {
    __shared__ int2 sc[G2CAP];
    __shared__ int s_start, s_n, s_ov;
    const int tid = threadIdx.x;
    const int node0 = blockIdx.x * G2N;
    const int lastn = min(node0 + G2N, N_NODES) - 1;
    if (tid == 0) {
        int2 a = off2[node0];
        int2 b = off2[lastn];
        s_start = a.x;
        s_n = b.x + b.y - a.x;
        s_ov = *ocur;
    }
    __syncthreads();
    const int start = s_start, n = s_n, ov = min(s_ov, OCAP);
    const bool fit = (n <= G2CAP);
    if (fit) for (int i = tid; i < n; i += 256) sc[i] = csr[start + i];
    __syncthreads();

    const int node = node0 + (tid >> 2);
    const int og = tid & 3;
    if (node >= N_NODES) return;
    float d = dis[node];
    float4 self = *(const float4*)(h2 + (size_t)node * EMBED + og * 4);
    float4 bv = *(const float4*)(b2 + og * 4);
    float4 acc = make_float4(0.f, 0.f, 0.f, 0.f);

    int2 o = off2[node];
    for (int j = 0; j < o.y; ++j) {
        int2 v = fit ? sc[o.x - start + j] : csr[o.x + j];
        float w = __int_as_float(v.y);           // raw ew
        const float4 hv = *(const float4*)(h2 + (size_t)v.x * EMBED + og * 4);
        acc.x += hv.x * w; acc.y += hv.y * w; acc.z += hv.z * w; acc.w += hv.w * w;
    }
    float4 res = make_float4((acc.x + self.x) * d + bv.x,
                             (acc.y + self.y) * d + bv.y,
                             (acc.z + self.z) * d + bv.z,
                             (acc.w + self.w) * d + bv.w);
    if (ov > 0) {  // exact overflow fallback
        for (int q = 0; q < ov; ++q) {
            int4 t = olist[q];
            if (t.y == node) {
                float w = __int_as_float(t.z) * d;  // h2' includes dis[src]
                const float4 hv = *(const float4*)(h2 + (size_t)t.x * EMBED + og * 4);
                res.x += hv.x * w; res.y += hv.y * w;
                res.z += hv.z * w; res.w += hv.w * w;
            }
        }
    }
    *(float4*)(out + (size_t)node * EMBED + og * 4) = res;
}

extern "C" void kernel_launch(void* const* d_in, const int* in_sizes, int n_in,
                              void* d_out, int out_size, void* d_ws, size_t ws_size,
                              hipStream_t stream) {
    const float* x  = (const float*)d_in[0];
    const int*   ei = (const int*)d_in[1];  // [2, E] int32
    const float* ew = (const float*)d_in[2];
    const float* W1 = (const float*)d_in[3];
    const float* b1 = (const float*)d_in[4];
    const float* W2 = (const float*)d_in[5];
    const float* b2 = (const float*)d_in[6];
    float* out = (float*)d_out;

    const int* row = ei;            // source
    const int* col = ei + N_EDGES;  // target

    // ws layout:
    // off2[N] int2 | binned[NBIN*CAPB] int2 | deg[N] f32 |
    // offm[PBLK*OMS] int | ocur[4] int | olist[OCAP] int4 |
    // big: chunks[PBLK*PEPB] int2  ALIASES  h[32N] + h2[16N]
    int2*  off2   = (int2*)d_ws;
    int2*  binned = off2 + N_NODES;
    float* deg    = (float*)(binned + (size_t)NBIN * CAPB);
    int*   offm   = (int*)(deg + N_NODES);
    int*   ocur   = offm + (size_t)PBLK * OMS;
    int4*  olist  = (int4*)(ocur + 4);
    void*  big    = (void*)(olist + OCAP);
    int2*  chunks = (int2*)big;
    float* h      = (float*)big;               // alias: chunks dead before gemm1
    float* h2     = h + (size_t)N_NODES * HIDDEN;

    const int B = 256;
    const int gN = (N_NODES + B - 1) / B;
    const int gO = (OCAP + B - 1) / B;

    k_part<<<PBLK, B, 0, stream>>>(row, col, ew, offm, chunks, ocur);
    k_build<<<NBIN, B, 0, stream>>>(offm, chunks, binned, deg, off2, ocur, olist);
    k_degover<<<gO, B, 0, stream>>>(ocur, olist, deg);
    k_dis<<<gN, B, 0, stream>>>(deg);
    k_gemm1<<<(N_NODES + GR - 1) / GR, B, 0, stream>>>(x, W1, deg, h);
    k_gather1<<<N_NODES / G1N, B, 0, stream>>>(off2, binned, h, deg, b1, W2, ocur, olist, h2);
    k_gather2<<<(N_NODES + G2N - 1) / G2N, B, 0, stream>>>(off2, binned, h2, deg, b2, ocur, olist, out);
}

// Round 27
// 269.388 us; speedup vs baseline: 1.3820x; 1.0065x over previous
//
#include <hip/hip_runtime.h>
#include <hip/hip_bf16.h>

#define N_NODES 100000
#define N_EDGES 3200000
#define FEAT 256
#define HIDDEN 32
#define EMBED 16
#define NPB 128                                // nodes per bin
#define NBIN ((N_NODES + NPB - 1) / NPB)       // 782
#define CAPB 4608                              // bin capacity (mean 4096 + 8 sigma)
#define OCAP 8192                              // overflow list capacity
#define GR 128                                 // gemm1 tile rows
#define G1N 32                                 // nodes per gather1 block
#define G1CAP 2048                             // LDS entries
#define G2N 64                                 // nodes per gather2 block
#define G2CAP 3072                             // LDS entries
#define PEPB 3072                              // edges per partition block
#define PBLK ((N_EDGES + PEPB - 1) / PEPB)     // 1042
#define OMS 784                                // offm row stride (782 bins + sentinel + pad)
#define RPT 5                                  // runs per thread in k_build (5*256 >= 1042)
#define NSK (NPB * 16)                         // sub-keys: node x 16 src-tiles (1MB h'-tiles)

// ---------------- pass 1: per-block bin-grouped chunk + offset row ----------
__global__ __launch_bounds__(256, 4) void k_part(
        const int* __restrict__ row, const int* __restrict__ col,
        const float* __restrict__ ew, int* __restrict__ offm,
        int2* __restrict__ chunks, int* __restrict__ ocur) {
    __shared__ int2 sed[PEPB];                 // 24576 B staged edges (grouped)
    __shared__ int shist[NBIN];                // counts -> local excl offsets
    __shared__ int scur[NBIN];                 // scan scratch, then cursors
    const int tid = threadIdx.x;
    const int blk = blockIdx.x;
    const int e0 = blk * PEPB;
    const int ne = min(PEPB, N_EDGES - e0);
    if (blk == 0 && tid == 0) *ocur = 0;

    for (int i = tid; i < NBIN; i += 256) shist[i] = 0;
    __syncthreads();
    for (int i = tid; i < ne; i += 256) atomicAdd(&shist[col[e0 + i] >> 7], 1);
    __syncthreads();
    int l[4];
    int s = 0;
#pragma unroll
    for (int k = 0; k < 4; ++k) {
        int b = tid * 4 + k;
        l[k] = (b < NBIN) ? shist[b] : 0;
        s += l[k];
    }
    scur[tid] = s;
    __syncthreads();
    for (int d = 1; d < 256; d <<= 1) {
        int t = (tid >= d) ? scur[tid - d] : 0;
        __syncthreads();
        scur[tid] += t;
        __syncthreads();
    }
    int ex = scur[tid] - s;
    __syncthreads();
#pragma unroll
    for (int k = 0; k < 4; ++k) {
        int b = tid * 4 + k;
        if (b < NBIN) {
            shist[b] = ex;
            scur[b] = ex;
            ex += l[k];
        }
    }
    __syncthreads();
    for (int b = tid; b < NBIN; b += 256) offm[blk * OMS + b] = shist[b];
    if (tid == 0) offm[blk * OMS + NBIN] = ne;
    for (int i = tid; i < ne; i += 256) {
        int e = e0 + i;
        int c = col[e];
        int b = c >> 7;
        int p = atomicAdd(&scur[b], 1);        // LDS atomic
        sed[p] = make_int2(((c & (NPB - 1)) << 17) | row[e], __float_as_int(ew[e]));
    }
    __syncthreads();
    for (int i = tid; i < ne; i += 256) chunks[(size_t)blk * PEPB + i] = sed[i];
}

// ---------------- pass 2: per-bin gather-from-chunks + group + deg + off2 ----
// 16 src-tiles per node (1MB h'-granules): concurrent gather h-reads confined
// to a ~2MB sliding window (L2-resident). scnt doubles as regroup cursor.
__global__ __launch_bounds__(256) void k_build(
        const int* __restrict__ offm, const int2* __restrict__ chunks,
        int2* __restrict__ binned, float* __restrict__ deg,
        int2* __restrict__ off2, int* __restrict__ ocur, int4* __restrict__ olist) {
    __shared__ int2 se[CAPB];                      // 36864 B
    __shared__ int scnt[NSK];                      //  8192 B (offsets, then cursors)
    __shared__ float sdeg[NPB];
    __shared__ int spart[256];
    const int bin = blockIdx.x, tid = threadIdx.x;
    const size_t base = (size_t)bin * CAPB;

    for (int i = tid; i < NSK; i += 256) scnt[i] = 0;
    for (int i = tid; i < NPB; i += 256) sdeg[i] = 0.f;
    int st[RPT], ln[RPT];
    int s = 0;
#pragma unroll
    for (int r = 0; r < RPT; ++r) {
        int k = tid * RPT + r;
        int a = 0, b2 = 0;
        if (k < PBLK) {
            a = offm[k * OMS + bin];
            b2 = offm[k * OMS + bin + 1];
        }
        st[r] = a;
        ln[r] = b2 - a;
        s += ln[r];
    }
    spart[tid] = s;
    __syncthreads();
    for (int d = 1; d < 256; d <<= 1) {
        int t = (tid >= d) ? spart[tid - d] : 0;
        __syncthreads();
        spart[tid] += t;
        __syncthreads();
    }
    int ex = spart[tid] - s;
    const int nTot = spart[255];
    const int n = min(nTot, CAPB);
    int dp = ex;
#pragma unroll
    for (int r = 0; r < RPT; ++r) {
        int k = tid * RPT + r;
        if (k < PBLK) {
            const int2* src = chunks + (size_t)k * PEPB + st[r];
            for (int j = 0; j < ln[r]; ++j) {
                int2 v = src[j];
                int lc = v.x >> 17;
                int dst = dp + j;
                if (dst < CAPB) {
                    se[dst] = v;
                    atomicAdd(&scnt[lc * 16 + ((v.x & 0x1FFFF) >> 13)], 1);
                    atomicAdd(&sdeg[lc], __int_as_float(v.y));
                } else {
                    int q = atomicAdd(ocur, 1);
                    if (q < OCAP)
                        olist[q] = make_int4(v.x & 0x1FFFF, bin * NPB + lc, v.y, 0);
                }
            }
            dp += ln[r];
        }
    }
    __syncthreads();
    // scan over 2048 sub-keys: 8 keys/thread + block scan of partials
    int l8[8];
    int s2 = 0;
#pragma unroll
    for (int k = 0; k < 8; ++k) {
        l8[k] = scnt[tid * 8 + k];
        s2 += l8[k];
    }
    spart[tid] = s2;
    __syncthreads();
    for (int d = 1; d < 256; d <<= 1) {
        int t = (tid >= d) ? spart[tid - d] : 0;
        __syncthreads();
        spart[tid] += t;
        __syncthreads();
    }
    int ex2 = spart[tid] - s2;
#pragma unroll
    for (int k = 0; k < 8; ++k) {
        scnt[tid * 8 + k] = ex2;
        ex2 += l8[k];
    }
    __syncthreads();
    if (tid < NPB) {
        int node = bin * NPB + tid;
        if (node < N_NODES) {
            int stn = scnt[tid * 16];
            int en = (tid == NPB - 1) ? n : scnt[(tid + 1) * 16];
            off2[node] = make_int2((int)base + stn, en - stn);
            deg[node] = sdeg[tid] + 1.0f;  // + self loop
        }
    }
    __syncthreads();   // off2/en reads done; scnt now reusable as cursors
    for (int i = tid; i < n; i += 256) {
        int2 v = se[i];
        int lc = v.x >> 17, src2 = v.x & 0x1FFFF;
        int p = atomicAdd(&scnt[lc * 16 + (src2 >> 13)], 1);  // LDS atomic
        binned[base + p] = make_int2(src2, v.y);              // {src, raw ew}
    }
}

__global__ void k_degover(const int* __restrict__ ocur, const int4* __restrict__ olist,
                          float* __restrict__ deg) {
    int p = blockIdx.x * blockDim.x + threadIdx.x;
    int n = min(*ocur, OCAP);
    if (p < n) { int4 t = olist[p]; unsafeAtomicAdd(&deg[t.y], __int_as_float(t.z)); }
}

__global__ void k_dis(float* __restrict__ deg) {
    int i = blockIdx.x * blockDim.x + threadIdx.x;
    if (i < N_NODES) {
        float d = deg[i];
        deg[i] = (d > 0.0f) ? rsqrtf(d) : 0.0f;
    }
}

// ---------------- layer 1 GEMM: h' = (x @ W1^T) * dis, software-pipelined ---
__global__ __launch_bounds__(256) void k_gemm1(
        const float* __restrict__ x, const float* __restrict__ W1,
        const float* __restrict__ dis, float* __restrict__ h) {
    __shared__ float sx[GR][36];       // 18432 B
    __shared__ float sw[HIDDEN][260];  // 33280 B

    const int tid = threadIdx.x;
    const size_t base = (size_t)blockIdx.x * GR;
    const float4* x4 = (const float4*)x;
    const float4* w4 = (const float4*)W1;
    const int rs = tid >> 3;
    const int ks = tid & 7;

    for (int i = tid; i < HIDDEN * 64; i += 256) {
        int f = i >> 6, kq = i & 63;
        *(float4*)&sw[f][kq * 4] = w4[f * 64 + kq];
    }
    float4 stg[4];
#pragma unroll
    for (int m = 0; m < 4; ++m) {
        int rr = rs + 32 * m;
        stg[m] = make_float4(0.f, 0.f, 0.f, 0.f);
        if (base + rr < N_NODES) stg[m] = x4[(base + rr) * 64 + ks];
    }
#pragma unroll
    for (int m = 0; m < 4; ++m) *(float4*)&sx[rs + 32 * m][ks * 4] = stg[m];
    __syncthreads();

    const int r0 = tid >> 3;
    const int c0 = tid & 7;
    float acc[4][4] = {};

    for (int p = 0; p < 8; ++p) {
        if (p < 7) {
#pragma unroll
            for (int m = 0; m < 4; ++m) {
                int rr = rs + 32 * m;
                stg[m] = make_float4(0.f, 0.f, 0.f, 0.f);
                if (base + rr < N_NODES) stg[m] = x4[(base + rr) * 64 + (p + 1) * 8 + ks];
            }
        }
#pragma unroll
        for (int kq = 0; kq < 8; ++kq) {
            float4 xa[4], wv[4];
#pragma unroll
            for (int m = 0; m < 4; ++m) xa[m] = *(const float4*)&sx[r0 + 32 * m][kq * 4];
#pragma unroll
            for (int j = 0; j < 4; ++j) wv[j] = *(const float4*)&sw[c0 + 8 * j][(p * 8 + kq) * 4];
#pragma unroll
            for (int m = 0; m < 4; ++m)
#pragma unroll
                for (int j = 0; j < 4; ++j)
                    acc[m][j] += xa[m].x * wv[j].x + xa[m].y * wv[j].y +
                                 xa[m].z * wv[j].z + xa[m].w * wv[j].w;
        }
        __syncthreads();
        if (p < 7) {
#pragma unroll
            for (int m = 0; m < 4; ++m) *(float4*)&sx[rs + 32 * m][ks * 4] = stg[m];
            __syncthreads();
        }
    }

#pragma unroll
    for (int m = 0; m < 4; ++m) {
        size_t r = base + r0 + 32 * m;
        if (r < N_NODES) {
            float ds = dis[r];
#pragma unroll
            for (int j = 0; j < 4; ++j) h[r * HIDDEN + c0 + 8 * j] = acc[m][j] * ds;
        }
    }
}

// ---- FUSED layer-1 gather + gemm2 (h is pre-scaled h' = h*dis) ----
__global__ __launch_bounds__(256) void k_gather1(
        const int2* __restrict__ off2, const int2* __restrict__ csr,
        const float* __restrict__ h, const float* __restrict__ dis,
        const float* __restrict__ b1, const float* __restrict__ W2,
        const int* __restrict__ ocur, const int4* __restrict__ olist,
        float* __restrict__ h2) {
    __shared__ int2 sc[G1CAP];                 // 16384 B csr window
    __shared__ float sw2[EMBED][HIDDEN + 1];   //  2112 B (stride 33)
    __shared__ float sout[G1N][HIDDEN + 1];    //  4224 B relu(out1)
    __shared__ int s_start, s_n, s_ov;
    const int tid = threadIdx.x;
    const int node0 = blockIdx.x * G1N;        // 100000 = 32*3125 exact
    if (tid == 0) {
        int2 a = off2[node0];
        int2 b = off2[node0 + G1N - 1];
        s_start = a.x;
        s_n = b.x + b.y - a.x;
        s_ov = *ocur;
    }
    for (int i = tid; i < EMBED * HIDDEN; i += 256) sw2[i >> 5][i & 31] = W2[i];
    __syncthreads();
    const int start = s_start, n = s_n, ov = min(s_ov, OCAP);
    const bool fit = (n <= G1CAP);
    if (fit) for (int i = tid; i < n; i += 256) sc[i] = csr[start + i];
    __syncthreads();

    const int node = node0 + (tid >> 3);
    const int og = tid & 7;
    float d = dis[node];
    float4 self = *(const float4*)(h + (size_t)node * HIDDEN + og * 4);
    float4 bv = *(const float4*)(b1 + og * 4);
    float4 acc = make_float4(0.f, 0.f, 0.f, 0.f);

    int2 o = off2[node];
    for (int j = 0; j < o.y; ++j) {
        int2 v = fit ? sc[o.x - start + j] : csr[o.x + j];
        float w = __int_as_float(v.y);           // raw ew
        const float4 hv = *(const float4*)(h + (size_t)v.x * HIDDEN + og * 4);
        acc.x += hv.x * w; acc.y += hv.y * w; acc.z += hv.z * w; acc.w += hv.w * w;
    }
    float4 res = make_float4((acc.x + self.x) * d + bv.x,
                             (acc.y + self.y) * d + bv.y,
                             (acc.z + self.z) * d + bv.z,
                             (acc.w + self.w) * d + bv.w);
    if (ov > 0) {  // exact overflow fallback (never taken in practice)
        for (int q = 0; q < ov; ++q) {
            int4 t = olist[q];
            if (t.y == node) {
                float w = __int_as_float(t.z) * d;  // h' includes dis[src]
                const float4 hv = *(const float4*)(h + (size_t)t.x * HIDDEN + og * 4);
                res.x += hv.x * w; res.y += hv.y * w;
                res.z += hv.z * w; res.w += hv.w * w;
            }
        }
    }
    // relu + stage
    *(float4*)&sout[tid >> 3][og * 4] =
        make_float4(fmaxf(res.x, 0.f), fmaxf(res.y, 0.f),
                    fmaxf(res.z, 0.f), fmaxf(res.w, 0.f));
    __syncthreads();
    // h2' = (relu(out1) @ W2^T) * dis : 32 nodes x 16 feats, 2 per thread
    const int n2 = tid >> 3;
    const int f2 = (tid & 7) * 2;
    float a0 = 0.f, a1 = 0.f;
#pragma unroll
    for (int k = 0; k < HIDDEN; ++k) {
        float r = sout[n2][k];
        a0 += r * sw2[f2][k];
        a1 += r * sw2[f2 + 1][k];
    }
    h2[(size_t)(node0 + n2) * EMBED + f2] = a0 * d;
    h2[(size_t)(node0 + n2) * EMBED + f2 + 1] = a1 * d;
}

// ---- layer 2 gather (h2 is pre-scaled h2' = h2*dis): out = gcn2 ----
__global__ __launch_bounds__(256) void k_gather2(
        const int2* __restrict__ off2, const int2* __restrict__ csr,
        const float* __restrict__ h2, const float* __restrict__ dis,
        const float* __restrict__ b2, const int* __restrict__ ocur,
        const int4* __restrict__ olist, float* __restrict__ out) {
    __shared__ int2 sc[G2CAP];
    __shared__ int s_start, s_n, s_ov;
    const int tid = threadIdx.x;
    const int node0 = blockIdx.x * G2N;
    const int lastn = min(node0 + G2N, N_NODES) - 1;
    if (tid == 0) {
        int2 a = off2[node0];
        int2 b = off2[lastn];
        s_start = a.x;
        s_n = b.x + b.y - a.x;
        s_ov = *ocur;
    }
    __syncthreads();
    const int start = s_start, n = s_n, ov = min(s_ov, OCAP);
    const bool fit = (n <= G2CAP);
    if (fit) for (int i = tid; i < n; i += 256) sc[i] = csr[start + i];
    __syncthreads();

    const int node = node0 + (tid >> 2);
    const int og = tid & 3;
    if (node >= N_NODES) return;
    float d = dis[node];
    float4 self = *(const float4*)(h2 + (size_t)node * EMBED + og * 4);
    float4 bv = *(const float4*)(b2 + og * 4);
    float4 acc = make_float4(0.f, 0.f, 0.f, 0.f);

    int2 o = off2[node];
    for (int j = 0; j < o.y; ++j) {
        int2 v = fit ? sc[o.x - start + j] : csr[o.x + j];
        float w = __int_as_float(v.y);           // raw ew
        const float4 hv = *(const float4*)(h2 + (size_t)v.x * EMBED + og * 4);
        acc.x += hv.x * w; acc.y += hv.y * w; acc.z += hv.z * w; acc.w += hv.w * w;
    }
    float4 res = make_float4((acc.x + self.x) * d + bv.x,
                             (acc.y + self.y) * d + bv.y,
                             (acc.z + self.z) * d + bv.z,
                             (acc.w + self.w) * d + bv.w);
    if (ov > 0) {  // exact overflow fallback
        for (int q = 0; q < ov; ++q) {
            int4 t = olist[q];
            if (t.y == node) {
                float w = __int_as_float(t.z) * d;  // h2' includes dis[src]
                const float4 hv = *(const float4*)(h2 + (size_t)t.x * EMBED + og * 4);
                res.x += hv.x * w; res.y += hv.y * w;
                res.z += hv.z * w; res.w += hv.w * w;
            }
        }
    }
    *(float4*)(out + (size_t)node * EMBED + og * 4) = res;
}

extern "C" void kernel_launch(void* const* d_in, const int* in_sizes, int n_in,
                              void* d_out, int out_size, void* d_ws, size_t ws_size,
                              hipStream_t stream) {
    const float* x  = (const float*)d_in[0];
    const int*   ei = (const int*)d_in[1];  // [2, E] int32
    const float* ew = (const float*)d_in[2];
    const float* W1 = (const float*)d_in[3];
    const float* b1 = (const float*)d_in[4];
    const float* W2 = (const float*)d_in[5];
    const float* b2 = (const float*)d_in[6];
    float* out = (float*)d_out;

    const int* row = ei;            // source
    const int* col = ei + N_EDGES;  // target

    // ws layout:
    // off2[N] int2 | binned[NBIN*CAPB] int2 | deg[N] f32 |
    // offm[PBLK*OMS] int | ocur[4] int | olist[OCAP] int4 |
    // big: chunks[PBLK*PEPB] int2  ALIASES  h[32N] + h2[16N]
    int2*  off2   = (int2*)d_ws;
    int2*  binned = off2 + N_NODES;
    float* deg    = (float*)(binned + (size_t)NBIN * CAPB);
    int*   offm   = (int*)(deg + N_NODES);
    int*   ocur   = offm + (size_t)PBLK * OMS;
    int4*  olist  = (int4*)(ocur + 4);
    void*  big    = (void*)(olist + OCAP);
    int2*  chunks = (int2*)big;
    float* h      = (float*)big;               // alias: chunks dead before gemm1
    float* h2     = h + (size_t)N_NODES * HIDDEN;

    const int B = 256;
    const int gN = (N_NODES + B - 1) / B;
    const int gO = (OCAP + B - 1) / B;

    k_part<<<PBLK, B, 0, stream>>>(row, col, ew, offm, chunks, ocur);
    k_build<<<NBIN, B, 0, stream>>>(offm, chunks, binned, deg, off2, ocur, olist);
    k_degover<<<gO, B, 0, stream>>>(ocur, olist, deg);
    k_dis<<<gN, B, 0, stream>>>(deg);
    k_gemm1<<<(N_NODES + GR - 1) / GR, B, 0, stream>>>(x, W1, deg, h);
    k_gather1<<<N_NODES / G1N, B, 0, stream>>>(off2, binned, h, deg, b1, W2, ocur, olist, h2);
    k_gather2<<<(N_NODES + G2N - 1) / G2N, B, 0, stream>>>(off2, binned, h2, deg, b2, ocur, olist, out);
}

// Round 28
// 266.168 us; speedup vs baseline: 1.3987x; 1.0121x over previous
//
#include <hip/hip_runtime.h>
#include <hip/hip_bf16.h>

#define N_NODES 100000
#define N_EDGES 3200000
#define FEAT 256
#define HIDDEN 32
#define EMBED 16
#define NPB 128                                // nodes per bin
#define NBIN ((N_NODES + NPB - 1) / NPB)       // 782
#define CAPB 4608                              // bin capacity (mean 4096 + 8 sigma)
#define OCAP 8192                              // overflow list capacity
#define GR 128                                 // gemm1 tile rows
#define G1N 32                                 // nodes per gather1 block
#define G1CAP 2048                             // LDS entries
#define G2N 64                                 // nodes per gather2 block
#define G2CAP 3072                             // LDS entries
#define PEPB 3072                              // edges per partition block
#define PBLK ((N_EDGES + PEPB - 1) / PEPB)     // 1042
#define OMS 784                                // offm row stride (782 bins + sentinel + pad)
#define RPT 5                                  // runs per thread in k_build (5*256 >= 1042)
#define NSK (NPB * 16)                         // sub-keys: node x 16 src-tiles

// ---------------- pass 1: per-block bin-grouped chunk + offset row ----------
__global__ __launch_bounds__(256, 4) void k_part(
        const int* __restrict__ row, const int* __restrict__ col,
        const float* __restrict__ ew, int* __restrict__ offm,
        int2* __restrict__ chunks, int* __restrict__ ocur) {
    __shared__ int2 sed[PEPB];                 // 24576 B staged edges (grouped)
    __shared__ int shist[NBIN];                // counts -> local excl offsets
    __shared__ int scur[NBIN];                 // scan scratch, then cursors
    const int tid = threadIdx.x;
    const int blk = blockIdx.x;
    const int e0 = blk * PEPB;
    const int ne = min(PEPB, N_EDGES - e0);
    if (blk == 0 && tid == 0) *ocur = 0;

    for (int i = tid; i < NBIN; i += 256) shist[i] = 0;
    __syncthreads();
    for (int i = tid; i < ne; i += 256) atomicAdd(&shist[col[e0 + i] >> 7], 1);
    __syncthreads();
    int l[4];
    int s = 0;
#pragma unroll
    for (int k = 0; k < 4; ++k) {
        int b = tid * 4 + k;
        l[k] = (b < NBIN) ? shist[b] : 0;
        s += l[k];
    }
    scur[tid] = s;
    __syncthreads();
    for (int d = 1; d < 256; d <<= 1) {
        int t = (tid >= d) ? scur[tid - d] : 0;
        __syncthreads();
        scur[tid] += t;
        __syncthreads();
    }
    int ex = scur[tid] - s;
    __syncthreads();
#pragma unroll
    for (int k = 0; k < 4; ++k) {
        int b = tid * 4 + k;
        if (b < NBIN) {
            shist[b] = ex;
            scur[b] = ex;
            ex += l[k];
        }
    }
    __syncthreads();
    for (int b = tid; b < NBIN; b += 256) offm[blk * OMS + b] = shist[b];
    if (tid == 0) offm[blk * OMS + NBIN] = ne;
    for (int i = tid; i < ne; i += 256) {
        int e = e0 + i;
        int c = col[e];
        int b = c >> 7;
        int p = atomicAdd(&scur[b], 1);        // LDS atomic
        sed[p] = make_int2(((c & (NPB - 1)) << 17) | row[e], __float_as_int(ew[e]));
    }
    __syncthreads();
    for (int i = tid; i < ne; i += 256) chunks[(size_t)blk * PEPB + i] = sed[i];
}

// ---------------- pass 2: per-bin gather + group + FULL deg->dis + off2 ----
// Every edge targeting a node is in its bin (incl. overflow, which is counted
// into sdeg at the divert site), so dis = rsqrt(deg) is computed HERE:
// k_degover and k_dis kernels are deleted.
__global__ __launch_bounds__(256) void k_build(
        const int* __restrict__ offm, const int2* __restrict__ chunks,
        int2* __restrict__ binned, float* __restrict__ dis,
        int2* __restrict__ off2, int* __restrict__ ocur, int4* __restrict__ olist) {
    __shared__ int2 se[CAPB];                      // 36864 B
    __shared__ int scnt[NSK];                      //  8192 B (offsets, then cursors)
    __shared__ float sdeg[NPB];
    __shared__ int spart[256];
    const int bin = blockIdx.x, tid = threadIdx.x;
    const size_t base = (size_t)bin * CAPB;

    for (int i = tid; i < NSK; i += 256) scnt[i] = 0;
    for (int i = tid; i < NPB; i += 256) sdeg[i] = 0.f;
    int st[RPT], ln[RPT];
    int s = 0;
#pragma unroll
    for (int r = 0; r < RPT; ++r) {
        int k = tid * RPT + r;
        int a = 0, b2 = 0;
        if (k < PBLK) {
            a = offm[k * OMS + bin];
            b2 = offm[k * OMS + bin + 1];
        }
        st[r] = a;
        ln[r] = b2 - a;
        s += ln[r];
    }
    spart[tid] = s;
    __syncthreads();
    for (int d = 1; d < 256; d <<= 1) {
        int t = (tid >= d) ? spart[tid - d] : 0;
        __syncthreads();
        spart[tid] += t;
        __syncthreads();
    }
    int ex = spart[tid] - s;
    const int nTot = spart[255];
    const int n = min(nTot, CAPB);
    int dp = ex;
#pragma unroll
    for (int r = 0; r < RPT; ++r) {
        int k = tid * RPT + r;
        if (k < PBLK) {
            const int2* src = chunks + (size_t)k * PEPB + st[r];
            for (int j = 0; j < ln[r]; ++j) {
                int2 v = src[j];
                int lc = v.x >> 17;
                int dst = dp + j;
                atomicAdd(&sdeg[lc], __int_as_float(v.y));  // ALL edges count
                if (dst < CAPB) {
                    se[dst] = v;
                    atomicAdd(&scnt[lc * 16 + ((v.x & 0x1FFFF) >> 13)], 1);
                } else {
                    int q = atomicAdd(ocur, 1);
                    if (q < OCAP)
                        olist[q] = make_int4(v.x & 0x1FFFF, bin * NPB + lc, v.y, 0);
                }
            }
            dp += ln[r];
        }
    }
    __syncthreads();
    // scan over 2048 sub-keys: 8 keys/thread + block scan of partials
    int l8[8];
    int s2 = 0;
#pragma unroll
    for (int k = 0; k < 8; ++k) {
        l8[k] = scnt[tid * 8 + k];
        s2 += l8[k];
    }
    spart[tid] = s2;
    __syncthreads();
    for (int d = 1; d < 256; d <<= 1) {
        int t = (tid >= d) ? spart[tid - d] : 0;
        __syncthreads();
        spart[tid] += t;
        __syncthreads();
    }
    int ex2 = spart[tid] - s2;
#pragma unroll
    for (int k = 0; k < 8; ++k) {
        scnt[tid * 8 + k] = ex2;
        ex2 += l8[k];
    }
    __syncthreads();
    if (tid < NPB) {
        int node = bin * NPB + tid;
        if (node < N_NODES) {
            int stn = scnt[tid * 16];
            int en = (tid == NPB - 1) ? n : scnt[(tid + 1) * 16];
            off2[node] = make_int2((int)base + stn, en - stn);
            float dg = sdeg[tid] + 1.0f;   // + self loop; always > 0
            dis[node] = rsqrtf(dg);
        }
    }
    __syncthreads();   // off2/en reads done; scnt now reusable as cursors
    for (int i = tid; i < n; i += 256) {
        int2 v = se[i];
        int lc = v.x >> 17, src2 = v.x & 0x1FFFF;
        int p = atomicAdd(&scnt[lc * 16 + (src2 >> 13)], 1);  // LDS atomic
        binned[base + p] = make_int2(src2, v.y);              // {src, raw ew}
    }
}

// ---------------- layer 1 GEMM: h' = (x @ W1^T) * dis, software-pipelined ---
__global__ __launch_bounds__(256) void k_gemm1(
        const float* __restrict__ x, const float* __restrict__ W1,
        const float* __restrict__ dis, float* __restrict__ h) {
    __shared__ float sx[GR][36];       // 18432 B
    __shared__ float sw[HIDDEN][260];  // 33280 B

    const int tid = threadIdx.x;
    const size_t base = (size_t)blockIdx.x * GR;
    const float4* x4 = (const float4*)x;
    const float4* w4 = (const float4*)W1;
    const int rs = tid >> 3;
    const int ks = tid & 7;

    for (int i = tid; i < HIDDEN * 64; i += 256) {
        int f = i >> 6, kq = i & 63;
        *(float4*)&sw[f][kq * 4] = w4[f * 64 + kq];
    }
    float4 stg[4];
#pragma unroll
    for (int m = 0; m < 4; ++m) {
        int rr = rs + 32 * m;
        stg[m] = make_float4(0.f, 0.f, 0.f, 0.f);
        if (base + rr < N_NODES) stg[m] = x4[(base + rr) * 64 + ks];
    }
#pragma unroll
    for (int m = 0; m < 4; ++m) *(float4*)&sx[rs + 32 * m][ks * 4] = stg[m];
    __syncthreads();

    const int r0 = tid >> 3;
    const int c0 = tid & 7;
    float acc[4][4] = {};

    for (int p = 0; p < 8; ++p) {
        if (p < 7) {
#pragma unroll
            for (int m = 0; m < 4; ++m) {
                int rr = rs + 32 * m;
                stg[m] = make_float4(0.f, 0.f, 0.f, 0.f);
                if (base + rr < N_NODES) stg[m] = x4[(base + rr) * 64 + (p + 1) * 8 + ks];
            }
        }
#pragma unroll
        for (int kq = 0; kq < 8; ++kq) {
            float4 xa[4], wv[4];
#pragma unroll
            for (int m = 0; m < 4; ++m) xa[m] = *(const float4*)&sx[r0 + 32 * m][kq * 4];
#pragma unroll
            for (int j = 0; j < 4; ++j) wv[j] = *(const float4*)&sw[c0 + 8 * j][(p * 8 + kq) * 4];
#pragma unroll
            for (int m = 0; m < 4; ++m)
#pragma unroll
                for (int j = 0; j < 4; ++j)
                    acc[m][j] += xa[m].x * wv[j].x + xa[m].y * wv[j].y +
                                 xa[m].z * wv[j].z + xa[m].w * wv[j].w;
        }
        __syncthreads();
        if (p < 7) {
#pragma unroll
            for (int m = 0; m < 4; ++m) *(float4*)&sx[rs + 32 * m][ks * 4] = stg[m];
            __syncthreads();
        }
    }

#pragma unroll
    for (int m = 0; m < 4; ++m) {
        size_t r = base + r0 + 32 * m;
        if (r < N_NODES) {
            float ds = dis[r];
#pragma unroll
            for (int j = 0; j < 4; ++j) h[r * HIDDEN + c0 + 8 * j] = acc[m][j] * ds;
        }
    }
}

// ---- FUSED layer-1 gather + gemm2 (h is pre-scaled h' = h*dis) ----
__global__ __launch_bounds__(256) void k_gather1(
        const int2* __restrict__ off2, const int2* __restrict__ csr,
        const float* __restrict__ h, const float* __restrict__ dis,
        const float* __restrict__ b1, const float* __restrict__ W2,
        const int* __restrict__ ocur, const int4* __restrict__ olist,
        float* __restrict__ h2) {
    __shared__ int2 sc[G1CAP];                 // 16384 B csr window
    __shared__ float sw2[EMBED][HIDDEN + 1];   //  2112 B (stride 33)
    __shared__ float sout[G1N][HIDDEN + 1];    //  4224 B relu(out1)
    __shared__ int s_start, s_n, s_ov;
    const int tid = threadIdx.x;
    const int node0 = blockIdx.x * G1N;        // 100000 = 32*3125 exact
    if (tid == 0) {
        int2 a = off2[node0];
        int2 b = off2[node0 + G1N - 1];
        s_start = a.x;
        s_n = b.x + b.y - a.x;
        s_ov = *ocur;
    }
    for (int i = tid; i < EMBED * HIDDEN; i += 256) sw2[i >> 5][i & 31] = W2[i];
    __syncthreads();
    const int start = s_start, n = s_n, ov = min(s_ov, OCAP);
    const bool fit = (n <= G1CAP);
    if (fit) for (int i = tid; i < n; i += 256) sc[i] = csr[start + i];
    __syncthreads();

    const int node = node0 + (tid >> 3);
    const int og = tid & 7;
    float d = dis[node];
    float4 self = *(const float4*)(h + (size_t)node * HIDDEN + og * 4);
    float4 bv = *(const float4*)(b1 + og * 4);
    float4 acc = make_float4(0.f, 0.f, 0.f, 0.f);

    int2 o = off2[node];
    for (int j = 0; j < o.y; ++j) {
        int2 v = fit ? sc[o.x - start + j] : csr[o.x + j];
        float w = __int_as_float(v.y);           // raw ew
        const float4 hv = *(const float4*)(h + (size_t)v.x * HIDDEN + og * 4);
        acc.x += hv.x * w; acc.y += hv.y * w; acc.z += hv.z * w; acc.w += hv.w * w;
    }
    float4 res = make_float4((acc.x + self.x) * d + bv.x,
                             (acc.y + self.y) * d + bv.y,
                             (acc.z + self.z) * d + bv.z,
                             (acc.w + self.w) * d + bv.w);
    if (ov > 0) {  // exact overflow fallback (never taken in practice)
        for (int q = 0; q < ov; ++q) {
            int4 t = olist[q];
            if (t.y == node) {
                float w = __int_as_float(t.z) * d;  // h' includes dis[src]
                const float4 hv = *(const float4*)(h + (size_t)t.x * HIDDEN + og * 4);
                res.x += hv.x * w; res.y += hv.y * w;
                res.z += hv.z * w; res.w += hv.w * w;
            }
        }
    }
    // relu + stage
    *(float4*)&sout[tid >> 3][og * 4] =
        make_float4(fmaxf(res.x, 0.f), fmaxf(res.y, 0.f),
                    fmaxf(res.z, 0.f), fmaxf(res.w, 0.f));
    __syncthreads();
    // h2' = (relu(out1) @ W2^T) * dis : 32 nodes x 16 feats, 2 per thread
    const int n2 = tid >> 3;
    const int f2 = (tid & 7) * 2;
    float a0 = 0.f, a1 = 0.f;
#pragma unroll
    for (int k = 0; k < HIDDEN; ++k) {
        float r = sout[n2][k];
        a0 += r * sw2[f2][k];
        a1 += r * sw2[f2 + 1][k];
    }
    h2[(size_t)(node0 + n2) * EMBED + f2] = a0 * d;
    h2[(size_t)(node0 + n2) * EMBED + f2 + 1] = a1 * d;
}

// ---- layer 2 gather (h2 is pre-scaled h2' = h2*dis): out = gcn2 ----
__global__ __launch_bounds__(256) void k_gather2(
        const int2* __restrict__ off2, const int2* __restrict__ csr,
        const float* __restrict__ h2, const float* __restrict__ dis,
        const float* __restrict__ b2, const int* __restrict__ ocur,
        const int4* __restrict__ olist, float* __restrict__ out) {
    __shared__ int2 sc[G2CAP];
    __shared__ int s_start, s_n, s_ov;
    const int tid = threadIdx.x;
    const int node0 = blockIdx.x * G2N;
    const int lastn = min(node0 + G2N, N_NODES) - 1;
    if (tid == 0) {
        int2 a = off2[node0];
        int2 b = off2[lastn];
        s_start = a.x;
        s_n = b.x + b.y - a.x;
        s_ov = *ocur;
    }
    __syncthreads();
    const int start = s_start, n = s_n, ov = min(s_ov, OCAP);
    const bool fit = (n <= G2CAP);
    if (fit) for (int i = tid; i < n; i += 256) sc[i] = csr[start + i];
    __syncthreads();

    const int node = node0 + (tid >> 2);
    const int og = tid & 3;
    if (node >= N_NODES) return;
    float d = dis[node];
    float4 self = *(const float4*)(h2 + (size_t)node * EMBED + og * 4);
    float4 bv = *(const float4*)(b2 + og * 4);
    float4 acc = make_float4(0.f, 0.f, 0.f, 0.f);

    int2 o = off2[node];
    for (int j = 0; j < o.y; ++j) {
        int2 v = fit ? sc[o.x - start + j] : csr[o.x + j];
        float w = __int_as_float(v.y);           // raw ew
        const float4 hv = *(const float4*)(h2 + (size_t)v.x * EMBED + og * 4);
        acc.x += hv.x * w; acc.y += hv.y * w; acc.z += hv.z * w; acc.w += hv.w * w;
    }
    float4 res = make_float4((acc.x + self.x) * d + bv.x,
                             (acc.y + self.y) * d + bv.y,
                             (acc.z + self.z) * d + bv.z,
                             (acc.w + self.w) * d + bv.w);
    if (ov > 0) {  // exact overflow fallback
        for (int q = 0; q < ov; ++q) {
            int4 t = olist[q];
            if (t.y == node) {
                float w = __int_as_float(t.z) * d;  // h2' includes dis[src]
                const float4 hv = *(const float4*)(h2 + (size_t)t.x * EMBED + og * 4);
                res.x += hv.x * w; res.y += hv.y * w;
                res.z += hv.z * w; res.w += hv.w * w;
            }
        }
    }
    *(float4*)(out + (size_t)node * EMBED + og * 4) = res;
}

extern "C" void kernel_launch(void* const* d_in, const int* in_sizes, int n_in,
                              void* d_out, int out_size, void* d_ws, size_t ws_size,
                              hipStream_t stream) {
    const float* x  = (const float*)d_in[0];
    const int*   ei = (const int*)d_in[1];  // [2, E] int32
    const float* ew = (const float*)d_in[2];
    const float* W1 = (const float*)d_in[3];
    const float* b1 = (const float*)d_in[4];
    const float* W2 = (const float*)d_in[5];
    const float* b2 = (const float*)d_in[6];
    float* out = (float*)d_out;

    const int* row = ei;            // source
    const int* col = ei + N_EDGES;  // target

    // ws layout:
    // off2[N] int2 | binned[NBIN*CAPB] int2 | dis[N] f32 |
    // offm[PBLK*OMS] int | ocur[4] int | olist[OCAP] int4 |
    // big: chunks[PBLK*PEPB] int2  ALIASES  h[32N] + h2[16N]
    int2*  off2   = (int2*)d_ws;
    int2*  binned = off2 + N_NODES;
    float* dis    = (float*)(binned + (size_t)NBIN * CAPB);
    int*   offm   = (int*)(dis + N_NODES);
    int*   ocur   = offm + (size_t)PBLK * OMS;
    int4*  olist  = (int4*)(ocur + 4);
    void*  big    = (void*)(olist + OCAP);
    int2*  chunks = (int2*)big;
    float* h      = (float*)big;               // alias: chunks dead before gemm1
    float* h2     = h + (size_t)N_NODES * HIDDEN;

    const int B = 256;

    k_part<<<PBLK, B, 0, stream>>>(row, col, ew, offm, chunks, ocur);
    k_build<<<NBIN, B, 0, stream>>>(offm, chunks, binned, dis, off2, ocur, olist);
    k_gemm1<<<(N_NODES + GR - 1) / GR, B, 0, stream>>>(x, W1, dis, h);
    k_gather1<<<N_NODES / G1N, B, 0, stream>>>(off2, binned, h, dis, b1, W2, ocur, olist, h2);
    k_gather2<<<(N_NODES + G2N - 1) / G2N, B, 0, stream>>>(off2, binned, h2, dis, b2, ocur, olist, out);
}